// Round 6
// baseline (489.544 us; speedup 1.0000x reference)
//
#include <hip/hip_runtime.h>
#include <stdint.h>

// ---------------------------------------------------------------------------
// GCN 3-layer forward:  out = A_hat @ relu(A_hat @ relu(A_hat @ x W0 + b0) W1 + b1) W2 + b2
// A_hat = D^-1/2 (A + I) D^-1/2. With pre-scaled rows h'[r] = dinv[r]*h[r]:
//   out[c] = dinv[c] * ( sum_{edges r->c} h'[r] + h'[c] ) + b
//
// R2: agg FETCH == 8 XCD x sizeof(H) (random graph) -> H stored bf16.
// R3: one-shot scatter was 64B-partial-line bound -> bucketed 2-pass sort.
// R4: feature-sliced gather: slice slab per XCD L2. FETCH 195->60 MB.
// R8: pre-scale H by dinv at GEMM output -> agg per-edge work = gather+add.
// R9: 32-feat slices, uint2 gathers. R10: MFMA gemm (3-term bf16 split).
//   434us. agg slab 6.4MB > 4MB L2 -> FETCH 200MB, BW-bound 3.7TB/s.
// R11: src-half split: FETCH 55MB but 2x writes + 2x overhead = 82us. REVERT.
// R12: 4-lane x uint4 subgroups: VALU 38->25% but FETCH 229MB, dur 80us.
//   LESSON: agg is purely byte-bound at ~3.6TB/s random-line ceiling;
//   instruction count irrelevant; only lever is cutting HBM bytes.
// R13: 16-feat slices (3.2MB slab = L2-resident, R8 bytes) + 2-lane x uint4
//   subgroups (32 dests/wave, E/4 wave-instrs = R12 efficiency, full 32B row
//   per gather). gemm epilogue/SLICED_IN/agg64 follow the 16-feat layout.
//   Accum order per feature unchanged -> absmax bit-identical.
// ---------------------------------------------------------------------------

static inline size_t ws_align(size_t x) { return (x + 255) & ~(size_t)255; }

typedef float __f2 __attribute__((ext_vector_type(2)));
typedef float __f4 __attribute__((ext_vector_type(4)));
typedef __attribute__((ext_vector_type(8))) short short8v;
typedef __attribute__((ext_vector_type(4))) float f32x4;

__device__ __forceinline__ int eidx(const void* p, size_t i, int is64) {
  return is64 ? (int)((const long long*)p)[i] : ((const int*)p)[i];
}

__device__ __forceinline__ uint16_t f2bf(float f) {  // RNE float->bf16
  uint32_t u = __float_as_uint(f);
  u += 0x7fffu + ((u >> 16) & 1u);
  return (uint16_t)(u >> 16);
}
__device__ __forceinline__ float bf_lo(uint32_t h) { return __uint_as_float(h << 16); }
__device__ __forceinline__ float bf_hi(uint32_t h) { return __uint_as_float(h & 0xffff0000u); }

// Detect int64 vs int32 edge_index (little-endian: int64 high words are 0).
__global__ void detect_k(const int* ei, int* flag) {
  if (threadIdx.x == 0 && blockIdx.x == 0) {
    int allz = 1;
    for (int i = 1; i < 128; i += 2)
      if (ei[i] != 0) { allz = 0; break; }
    *flag = allz;
  }
}

// --- passA: bucket histogram via per-block LDS counters --------------------
__global__ __launch_bounds__(256) void passA_k(const void* ei, const int* __restrict__ flag,
                                               int* __restrict__ bucket_cnt, int E, int NB) {
  __shared__ int cnt[256];
  int t = threadIdx.x;
  cnt[t] = 0;
  __syncthreads();
  int is64 = *flag;
  for (int e = blockIdx.x * 256 + t; e < E; e += gridDim.x * 256) {
    int c = eidx(ei, (size_t)E + e, is64);
    atomicAdd(&cnt[c >> 9], 1);
  }
  __syncthreads();
  if (t < NB && cnt[t]) atomicAdd(&bucket_cnt[t], cnt[t]);
}

// --- bscan: exclusive scan of bucket_cnt -> bucket_offs; init gcursor ------
__global__ __launch_bounds__(256) void bscan_k(const int* __restrict__ bucket_cnt,
                                               int* __restrict__ bucket_offs,
                                               int* __restrict__ gcursor, int NB) {
  __shared__ int sh[256];
  int t = threadIdx.x;
  int v = (t < NB) ? bucket_cnt[t] : 0;
  sh[t] = v;
  __syncthreads();
  for (int off = 1; off < 256; off <<= 1) {
    int x = (t >= off) ? sh[t - off] : 0;
    __syncthreads();
    sh[t] += x;
    __syncthreads();
  }
  if (t < NB) {
    int excl = sh[t] - v;
    bucket_offs[t] = excl;
    gcursor[t] = excl;
  }
  if (t == NB - 1) bucket_offs[NB] = sh[t];
}

// --- passB: partition edges into bucket-contiguous epk_binned --------------
__global__ __launch_bounds__(256) void passB_k(const void* ei, const int* __restrict__ flag,
                                               int* __restrict__ gcursor,
                                               int2* __restrict__ epk_binned, int E, int NB) {
  __shared__ int2 sorted[4096];                       // 32 KB
  __shared__ int cnt[256], bbase[256], gb[256], cur[256];
  const int t = threadIdx.x;
  const int base = blockIdx.x * 4096;
  const int CH = min(4096, E - base);
  const int is64 = *flag;

  cnt[t] = 0;
  __syncthreads();
  for (int i = t; i < CH; i += 256) {
    int c = eidx(ei, (size_t)E + base + i, is64);
    atomicAdd(&cnt[c >> 9], 1);
  }
  __syncthreads();
  {
    int v = cnt[t];
    __shared__ int sh[256];
    sh[t] = v;
    __syncthreads();
    for (int off = 1; off < 256; off <<= 1) {
      int x = (t >= off) ? sh[t - off] : 0;
      __syncthreads();
      sh[t] += x;
      __syncthreads();
    }
    bbase[t] = sh[t] - v;
    gb[t] = (t < NB && v) ? atomicAdd(&gcursor[t], v) : 0;
    cur[t] = 0;
  }
  __syncthreads();
  for (int i = t; i < CH; i += 256) {
    int r = eidx(ei, (size_t)base + i, is64);
    int c = eidx(ei, (size_t)E + base + i, is64);
    int b = c >> 9;
    int rank = atomicAdd(&cur[b], 1);
    sorted[bbase[b] + rank] = make_int2(r, c);
  }
  __syncthreads();
  for (int i = t; i < CH; i += 256) {
    int2 v = sorted[i];
    int b = v.y >> 9;
    epk_binned[gb[b] + (i - bbase[b])] = v;
  }
}

// --- passC0: per-bucket degree count -> deg[] and offs[] (coalesced) -------
__global__ __launch_bounds__(256) void passC0_k(const int2* __restrict__ epk_binned,
                                                const int* __restrict__ bucket_offs,
                                                int* __restrict__ deg, int* __restrict__ offs,
                                                int n, int NB) {
  __shared__ int dcnt[512];
  __shared__ int s[256];
  const int t = threadIdx.x;
  const int b = blockIdx.x;
  dcnt[t] = 0; dcnt[t + 256] = 0;
  __syncthreads();
  const int lo = bucket_offs[b], hi = bucket_offs[b + 1];
  for (int i = lo + t; i < hi; i += 256)
    atomicAdd(&dcnt[epk_binned[i].y & 511], 1);
  __syncthreads();
  int d0 = dcnt[2 * t], d1 = dcnt[2 * t + 1];
  int pv = d0 + d1;
  s[t] = pv;
  __syncthreads();
  for (int off = 1; off < 256; off <<= 1) {
    int x = (t >= off) ? s[t - off] : 0;
    __syncthreads();
    s[t] += x;
    __syncthreads();
  }
  int pex = s[t] - pv;
  const int node0 = b << 9;
  int g0 = node0 + 2 * t, g1 = node0 + 2 * t + 1;
  if (g0 < n) { deg[g0] = d0; offs[g0] = lo + pex; }
  if (g1 < n) { deg[g1] = d1; offs[g1] = lo + pex + d0; }
  if (b == NB - 1 && t == 0) offs[n] = hi;
}

__global__ void dinv_k(const int* __restrict__ deg, float* __restrict__ dinv, int n) {
  int i = blockIdx.x * blockDim.x + threadIdx.x;
  if (i < n) dinv[i] = rsqrtf((float)deg[i] + 1.0f);  // +1 = self loop
}

// --- passC: final placement by exact dest; entry = plain src ---------------
__global__ __launch_bounds__(256) void passC_k(const int2* __restrict__ epk_binned,
                                               const int* __restrict__ bucket_offs,
                                               const int* __restrict__ offs,
                                               uint32_t* __restrict__ epk) {
  __shared__ int cur[512];
  const int t = threadIdx.x;
  const int b = blockIdx.x;
  cur[t] = 0; cur[t + 256] = 0;
  __syncthreads();
  const int lo = bucket_offs[b], hi = bucket_offs[b + 1];
  for (int i = lo + t; i < hi; i += 256) {
    int2 v = epk_binned[i];
    int pos = offs[v.y] + atomicAdd(&cur[v.y & 511], 1);
    epk[pos] = (uint32_t)v.x;
  }
}

// --- wprep: split W fp32 -> bf16 hi/lo MFMA fragments in global ------------
template <int COLS>
__global__ void wprep_k(const float* __restrict__ W, uint16_t* __restrict__ Wf) {
  constexpr int CT = COLS / 16;
  const int f = blockIdx.x;  // [0, 4*CT)
  const int kc = f / CT, ct = f % CT;
  const int l = threadIdx.x;  // 0..63
#pragma unroll
  for (int j = 0; j < 8; ++j) {
    int k = kc * 32 + (l >> 4) * 8 + j;
    int col = ct * 16 + (l & 15);
    float wv = W[(size_t)k * COLS + col];
    uint16_t hi = f2bf(wv);
    float res = wv - __uint_as_float((uint32_t)hi << 16);
    Wf[(size_t)f * 1024 + l * 8 + j] = hi;
    Wf[(size_t)f * 1024 + 512 + l * 8 + j] = f2bf(res);
  }
}

// --- MFMA GEMM: Hs (16-feat-sliced bf16) = dinv[row] * (X @ W) -------------
// X read dense (layer 0) or 16-feat-sliced fp32 (layers 1/2).
// H layout: slice ct (8 uint32 = 16 feats): HW[(ct*N + row)*8 + j].
template <int COLS, bool SLICED_IN>
__global__ __launch_bounds__(256) void gemm_k(const float* __restrict__ X,
                                              const uint16_t* __restrict__ Wf,
                                              const float* __restrict__ dinv,
                                              uint16_t* __restrict__ H, int N) {
  constexpr int CT = COLS / 16;
  __shared__ uint32_t Xp[128 * 32];  // 16 KB

  const int tid = threadIdx.x;
  const int l = tid & 63, w = tid >> 6;
  const int rowbase = blockIdx.x * 128;
  const float4* X4 = (const float4*)X;

  f32x4 acc[2][CT];
#pragma unroll
  for (int rt = 0; rt < 2; ++rt)
#pragma unroll
    for (int ct = 0; ct < CT; ++ct) acc[rt][ct] = (f32x4)0.f;

  for (int kc = 0; kc < 4; ++kc) {
    __syncthreads();
    // stage X chunk: 128 rows x 32 k, packed bf16 hi/lo, swizzled
#pragma unroll
    for (int t = 0; t < 4; ++t) {
      int i = tid + t * 256;  // 0..1023
      int r = i >> 3, q = i & 7;
      int gr = rowbase + r;
      if (gr >= N) gr = N - 1;
      float4 xv;
      if (SLICED_IN) {
        // 16-feat slices: k = kc*32 + q*4 -> slice 2*kc + (q>>2), quad q&3
        xv = X4[((size_t)(2 * kc + (q >> 2)) * N + gr) * 4 + (q & 3)];
      } else {
        xv = X4[(size_t)gr * 32 + kc * 8 + q];
      }
      float xs[4] = {xv.x, xv.y, xv.z, xv.w};
      uint32_t p[4];
#pragma unroll
      for (int e = 0; e < 4; ++e) {
        uint16_t hi = f2bf(xs[e]);
        float res = xs[e] - __uint_as_float((uint32_t)hi << 16);
        p[e] = ((uint32_t)hi << 16) | (uint32_t)f2bf(res);
      }
      int blk = q ^ (r & 7);
      *(uint4*)&Xp[r * 32 + blk * 4] = make_uint4(p[0], p[1], p[2], p[3]);
    }
    __syncthreads();

    // A fragments (2 row-tiles), unpack hi/lo via v_perm
    short8v ah[2], al[2];
#pragma unroll
    for (int rt = 0; rt < 2; ++rt) {
      int r = w * 32 + rt * 16 + (l & 15);
      int c = (r & 7) << 2;
      int b0 = ((l >> 4) * 8) ^ c;
      int b1 = ((l >> 4) * 8 + 4) ^ c;
      uint32_t ua[8];
      *(uint4*)&ua[0] = *(const uint4*)&Xp[r * 32 + b0];
      *(uint4*)&ua[4] = *(const uint4*)&Xp[r * 32 + b1];
      union { uint32_t d[4]; short8v v; } ch, cl;
#pragma unroll
      for (int p2 = 0; p2 < 4; ++p2) {
        ch.d[p2] = __builtin_amdgcn_perm(ua[2 * p2 + 1], ua[2 * p2], 0x07060302u);
        cl.d[p2] = __builtin_amdgcn_perm(ua[2 * p2 + 1], ua[2 * p2], 0x05040100u);
      }
      ah[rt] = ch.v;
      al[rt] = cl.v;
    }

    // B fragments from global (L2), 3-term mfma
#pragma unroll
    for (int ct = 0; ct < CT; ++ct) {
      size_t fo = (size_t)(kc * CT + ct) * 1024;
      short8v bh = *(const short8v*)(Wf + fo + l * 8);
      short8v bl = *(const short8v*)(Wf + fo + 512 + l * 8);
#pragma unroll
      for (int rt = 0; rt < 2; ++rt) {
        acc[rt][ct] = __builtin_amdgcn_mfma_f32_16x16x32_bf16(ah[rt], bh, acc[rt][ct], 0, 0, 0);
        acc[rt][ct] = __builtin_amdgcn_mfma_f32_16x16x32_bf16(al[rt], bh, acc[rt][ct], 0, 0, 0);
        acc[rt][ct] = __builtin_amdgcn_mfma_f32_16x16x32_bf16(ah[rt], bl, acc[rt][ct], 0, 0, 0);
      }
    }
  }

  // Epilogue: D col=lane&15, row=(lane>>4)*4+reg. Pair even/odd cols via
  // shfl_xor -> uint32 words; 16-feat slice ct -> HW[(ct*N+row)*8 + lc/2].
  uint32_t* HW = (uint32_t*)H;
  const int lq = l >> 4, lc = l & 15;
#pragma unroll
  for (int rt = 0; rt < 2; ++rt) {
#pragma unroll
    for (int q = 0; q < 4; ++q) {
      int row = rowbase + w * 32 + rt * 16 + lq * 4 + q;
      bool ok = row < N;
      float dv = ok ? dinv[row] : 0.f;
#pragma unroll
      for (int ct = 0; ct < CT; ++ct) {
        float v = acc[rt][ct][q] * dv;
        int b = (int)f2bf(v);
        int other = __shfl_xor(b, 1);
        if (ok && !(l & 1)) {
          uint32_t word = (uint32_t)b | ((uint32_t)other << 16);
          HW[((size_t)ct * N + row) * 8 + (lc >> 1)] = word;
        }
      }
    }
  }
}

// --- Sliced aggregate, 128 feats: 8 slices x 16 feats, slice = blockIdx&7 --
// R13: 2-lane subgroups, lane w gathers uint4 = feats 8w..8w+7.
// 2 lanes x 16B = full 32B row per (dest,edge); wave covers 32 dests.
// Slab = N*32B = 3.2MB per XCD -> L2-resident.
__global__ __launch_bounds__(256, 8) void agg128s_k(const uint32_t* __restrict__ HW,
                                                    const int* __restrict__ offs,
                                                    const uint32_t* __restrict__ epk,
                                                    const float* __restrict__ bias,
                                                    float* __restrict__ Aout,
                                                    int relu, int N) {
  const int s = blockIdx.x & 7;
  const int g = blockIdx.x >> 3;
  const int lane = threadIdx.x & 63;
  const int wid = threadIdx.x >> 6;
  const int d = lane >> 1, w = lane & 1;
  const int c = g * 128 + wid * 32 + d;
  if (c >= N) return;
  const uint32_t* Hs = HW + (size_t)s * N * 8;
  const int wq = 4 * w;
  int e0 = offs[c], e1 = offs[c + 1];
  float a0 = 0.f, a1 = 0.f, a2 = 0.f, a3 = 0.f;
  float a4 = 0.f, a5 = 0.f, a6 = 0.f, a7 = 0.f;
  int e = e0;
  for (; e + 4 <= e1; e += 4) {
    uint32_t p0 = epk[e], p1 = epk[e + 1], p2 = epk[e + 2], p3 = epk[e + 3];
    uint4 h0 = *(const uint4*)&Hs[(size_t)p0 * 8 + wq];
    uint4 h1 = *(const uint4*)&Hs[(size_t)p1 * 8 + wq];
    uint4 h2 = *(const uint4*)&Hs[(size_t)p2 * 8 + wq];
    uint4 h3 = *(const uint4*)&Hs[(size_t)p3 * 8 + wq];
    a0 += bf_lo(h0.x); a1 += bf_hi(h0.x); a2 += bf_lo(h0.y); a3 += bf_hi(h0.y);
    a4 += bf_lo(h0.z); a5 += bf_hi(h0.z); a6 += bf_lo(h0.w); a7 += bf_hi(h0.w);
    a0 += bf_lo(h1.x); a1 += bf_hi(h1.x); a2 += bf_lo(h1.y); a3 += bf_hi(h1.y);
    a4 += bf_lo(h1.z); a5 += bf_hi(h1.z); a6 += bf_lo(h1.w); a7 += bf_hi(h1.w);
    a0 += bf_lo(h2.x); a1 += bf_hi(h2.x); a2 += bf_lo(h2.y); a3 += bf_hi(h2.y);
    a4 += bf_lo(h2.z); a5 += bf_hi(h2.z); a6 += bf_lo(h2.w); a7 += bf_hi(h2.w);
    a0 += bf_lo(h3.x); a1 += bf_hi(h3.x); a2 += bf_lo(h3.y); a3 += bf_hi(h3.y);
    a4 += bf_lo(h3.z); a5 += bf_hi(h3.z); a6 += bf_lo(h3.w); a7 += bf_hi(h3.w);
  }
  for (; e < e1; ++e) {
    uint4 h = *(const uint4*)&Hs[(size_t)epk[e] * 8 + wq];
    a0 += bf_lo(h.x); a1 += bf_hi(h.x); a2 += bf_lo(h.y); a3 += bf_hi(h.y);
    a4 += bf_lo(h.z); a5 += bf_hi(h.z); a6 += bf_lo(h.w); a7 += bf_hi(h.w);
  }
  float dc = rsqrtf((float)(e1 - e0) + 1.f);
  uint4 hc = *(const uint4*)&Hs[(size_t)c * 8 + wq];
  const float* bs = bias + s * 16 + 8 * w;
  float r0 = fmaf(dc, a0 + bf_lo(hc.x), bs[0]);
  float r1 = fmaf(dc, a1 + bf_hi(hc.x), bs[1]);
  float r2 = fmaf(dc, a2 + bf_lo(hc.y), bs[2]);
  float r3 = fmaf(dc, a3 + bf_hi(hc.y), bs[3]);
  float r4 = fmaf(dc, a4 + bf_lo(hc.z), bs[4]);
  float r5 = fmaf(dc, a5 + bf_hi(hc.z), bs[5]);
  float r6 = fmaf(dc, a6 + bf_lo(hc.w), bs[6]);
  float r7 = fmaf(dc, a7 + bf_hi(hc.w), bs[7]);
  if (relu) {
    r0 = fmaxf(r0, 0.f); r1 = fmaxf(r1, 0.f); r2 = fmaxf(r2, 0.f); r3 = fmaxf(r3, 0.f);
    r4 = fmaxf(r4, 0.f); r5 = fmaxf(r5, 0.f); r6 = fmaxf(r6, 0.f); r7 = fmaxf(r7, 0.f);
  }
  float* OP = Aout + ((size_t)s * N + c) * 16 + 8 * w;
  __f4 lo4; lo4.x = r0; lo4.y = r1; lo4.z = r2; lo4.w = r3;
  __f4 hi4; hi4.x = r4; hi4.y = r5; hi4.z = r6; hi4.w = r7;
  __builtin_nontemporal_store(lo4, (__f4*)OP);
  __builtin_nontemporal_store(hi4, (__f4*)(OP + 4));
}

// --- Sliced aggregate, 64 feats: 4 slices x 16 on XCD pairs; dense out -----
// R13: 2-lane x uint4 subgroups (32 dests/wave).
__global__ __launch_bounds__(256, 8) void agg64s_k(const uint32_t* __restrict__ HW,
                                                   const int* __restrict__ offs,
                                                   const uint32_t* __restrict__ epk,
                                                   const float* __restrict__ bias,
                                                   float* __restrict__ out, int N) {
  const int r = blockIdx.x & 7;
  const int s = r >> 1;          // slice 0..3 (16 feats each)
  const int half = r & 1;
  const int ng = (N + 127) >> 7;
  const int nh = (ng + 1) >> 1;
  const int g = half * nh + (blockIdx.x >> 3);
  if (g >= ng) return;
  const int lane = threadIdx.x & 63;
  const int wid = threadIdx.x >> 6;
  const int d = lane >> 1, w = lane & 1;
  const int c = g * 128 + wid * 32 + d;
  if (c >= N) return;
  const uint32_t* Hs = HW + (size_t)s * N * 8;
  const int wq = 4 * w;
  int e0 = offs[c], e1 = offs[c + 1];
  float a0 = 0.f, a1 = 0.f, a2 = 0.f, a3 = 0.f;
  float a4 = 0.f, a5 = 0.f, a6 = 0.f, a7 = 0.f;
  int e = e0;
  for (; e + 4 <= e1; e += 4) {
    uint32_t p0 = epk[e], p1 = epk[e + 1], p2 = epk[e + 2], p3 = epk[e + 3];
    uint4 h0 = *(const uint4*)&Hs[(size_t)p0 * 8 + wq];
    uint4 h1 = *(const uint4*)&Hs[(size_t)p1 * 8 + wq];
    uint4 h2 = *(const uint4*)&Hs[(size_t)p2 * 8 + wq];
    uint4 h3 = *(const uint4*)&Hs[(size_t)p3 * 8 + wq];
    a0 += bf_lo(h0.x); a1 += bf_hi(h0.x); a2 += bf_lo(h0.y); a3 += bf_hi(h0.y);
    a4 += bf_lo(h0.z); a5 += bf_hi(h0.z); a6 += bf_lo(h0.w); a7 += bf_hi(h0.w);
    a0 += bf_lo(h1.x); a1 += bf_hi(h1.x); a2 += bf_lo(h1.y); a3 += bf_hi(h1.y);
    a4 += bf_lo(h1.z); a5 += bf_hi(h1.z); a6 += bf_lo(h1.w); a7 += bf_hi(h1.w);
    a0 += bf_lo(h2.x); a1 += bf_hi(h2.x); a2 += bf_lo(h2.y); a3 += bf_hi(h2.y);
    a4 += bf_lo(h2.z); a5 += bf_hi(h2.z); a6 += bf_lo(h2.w); a7 += bf_hi(h2.w);
    a0 += bf_lo(h3.x); a1 += bf_hi(h3.x); a2 += bf_lo(h3.y); a3 += bf_hi(h3.y);
    a4 += bf_lo(h3.z); a5 += bf_hi(h3.z); a6 += bf_lo(h3.w); a7 += bf_hi(h3.w);
  }
  for (; e < e1; ++e) {
    uint4 h = *(const uint4*)&Hs[(size_t)epk[e] * 8 + wq];
    a0 += bf_lo(h.x); a1 += bf_hi(h.x); a2 += bf_lo(h.y); a3 += bf_hi(h.y);
    a4 += bf_lo(h.z); a5 += bf_hi(h.z); a6 += bf_lo(h.w); a7 += bf_hi(h.w);
  }
  float dc = rsqrtf((float)(e1 - e0) + 1.f);
  uint4 hc = *(const uint4*)&Hs[(size_t)c * 8 + wq];
  const float* bs = bias + s * 16 + 8 * w;
  float r0 = fmaf(dc, a0 + bf_lo(hc.x), bs[0]);
  float r1 = fmaf(dc, a1 + bf_hi(hc.x), bs[1]);
  float r2 = fmaf(dc, a2 + bf_lo(hc.y), bs[2]);
  float r3 = fmaf(dc, a3 + bf_hi(hc.y), bs[3]);
  float r4 = fmaf(dc, a4 + bf_lo(hc.z), bs[4]);
  float r5 = fmaf(dc, a5 + bf_hi(hc.z), bs[5]);
  float r6 = fmaf(dc, a6 + bf_lo(hc.w), bs[6]);
  float r7 = fmaf(dc, a7 + bf_hi(hc.w), bs[7]);
  float* OP = out + (size_t)c * 64 + s * 16 + 8 * w;
  __f4 lo4; lo4.x = r0; lo4.y = r1; lo4.z = r2; lo4.w = r3;
  __f4 hi4; hi4.x = r4; hi4.y = r5; hi4.z = r6; hi4.w = r7;
  __builtin_nontemporal_store(lo4, (__f4*)OP);
  __builtin_nontemporal_store(hi4, (__f4*)(OP + 4));
}

extern "C" void kernel_launch(void* const* d_in, const int* in_sizes, int n_in,
                              void* d_out, int out_size, void* d_ws, size_t ws_size,
                              hipStream_t stream) {
  const float* x  = (const float*)d_in[0];
  const void*  ei = d_in[1];
  const float* W0 = (const float*)d_in[2];
  const float* b0 = (const float*)d_in[3];
  const float* W1 = (const float*)d_in[4];
  const float* b1 = (const float*)d_in[5];
  const float* W2 = (const float*)d_in[6];
  const float* b2 = (const float*)d_in[7];
  float* out = (float*)d_out;

  const int n = in_sizes[0] / 128;   // 100000
  const int E = in_sizes[1] / 2;     // 1600000
  const int NB = (n + 511) >> 9;     // buckets of 512 dests (NB <= 256)

  char* ws = (char*)d_ws;
  size_t off = 0;
  auto alloc = [&](size_t bytes) { char* p = ws + off; off = ws_align(off + bytes); return p; };
  int*      bucket_cnt  = (int*)alloc(256 * 4);
  int*      bucket_offs = (int*)alloc(257 * 4);
  int*      gcursor     = (int*)alloc(256 * 4);
  int*      deg         = (int*)alloc((size_t)n * 4);
  int*      offs        = (int*)alloc((size_t)(n + 1) * 4);
  float*    dinv        = (float*)alloc((size_t)n * 4);
  int*      flag        = (int*)alloc(4);
  uint16_t* wf0         = (uint16_t*)alloc(64 * 1024);
  uint16_t* wf1         = (uint16_t*)alloc(64 * 1024);
  uint16_t* wf2         = (uint16_t*)alloc(32 * 1024);
  int2*     epk_binned  = (int2*)alloc((size_t)E * 8);
  uint32_t* epk         = (uint32_t*)alloc((size_t)E * 4);
  uint16_t* hbuf        = (uint16_t*)alloc((size_t)n * 128 * 2);  // sliced bf16 H'
  float*    abuf        = (float*)alloc((size_t)n * 128 * 4);     // sliced fp32 acts
  (void)ws_size;

  hipMemsetAsync(bucket_cnt, 0, 256 * 4, stream);

  // W split/fragment prep (independent of graph passes)
  wprep_k<128><<<32, 64, 0, stream>>>(W0, wf0);
  wprep_k<128><<<32, 64, 0, stream>>>(W1, wf1);
  wprep_k<64><<<16, 64, 0, stream>>>(W2, wf2);

  detect_k<<<1, 64, 0, stream>>>((const int*)ei, flag);
  passA_k<<<512, 256, 0, stream>>>(ei, flag, bucket_cnt, E, NB);
  bscan_k<<<1, 256, 0, stream>>>(bucket_cnt, bucket_offs, gcursor, NB);
  passB_k<<<(E + 4095) / 4096, 256, 0, stream>>>(ei, flag, gcursor, epk_binned, E, NB);
  passC0_k<<<NB, 256, 0, stream>>>(epk_binned, bucket_offs, deg, offs, n, NB);
  dinv_k<<<(n + 255) / 256, 256, 0, stream>>>(deg, dinv, n);
  passC_k<<<NB, 256, 0, stream>>>(epk_binned, bucket_offs, offs, epk);

  const int gemm_blocks = (n + 127) / 128;
  const int agg128_blocks = 8 * ((n + 127) / 128);
  const int ng = (n + 127) >> 7, nh = (ng + 1) >> 1;
  const int agg64_blocks = 8 * nh;

  // Layer 0 (dense x input)
  gemm_k<128, false><<<gemm_blocks, 256, 0, stream>>>(x, wf0, dinv, hbuf, n);
  agg128s_k<<<agg128_blocks, 256, 0, stream>>>((const uint32_t*)hbuf, offs, epk, b0, abuf, 1, n);
  // Layer 1 (sliced activations)
  gemm_k<128, true><<<gemm_blocks, 256, 0, stream>>>(abuf, wf1, dinv, hbuf, n);
  agg128s_k<<<agg128_blocks, 256, 0, stream>>>((const uint32_t*)hbuf, offs, epk, b1, abuf, 1, n);
  // Layer 2 (no relu) -> d_out dense fp32
  gemm_k<64, true><<<gemm_blocks, 256, 0, stream>>>(abuf, wf2, dinv, hbuf, n);
  agg64s_k<<<agg64_blocks, 256, 0, stream>>>((const uint32_t*)hbuf, offs, epk, b2, out, n);
}

// Round 7
// 436.178 us; speedup vs baseline: 1.1224x; 1.1224x over previous
//
#include <hip/hip_runtime.h>
#include <stdint.h>

// ---------------------------------------------------------------------------
// GCN 3-layer forward:  out = A_hat @ relu(A_hat @ relu(A_hat @ x W0 + b0) W1 + b1) W2 + b2
// A_hat = D^-1/2 (A + I) D^-1/2. With pre-scaled rows h'[r] = dinv[r]*h[r]:
//   out[c] = dinv[c] * ( sum_{edges r->c} h'[r] + h'[c] ) + b
//
// R2: agg FETCH == 8 XCD x sizeof(H) (random graph) -> H stored bf16.
// R3: one-shot scatter was 64B-partial-line bound -> bucketed 2-pass sort.
// R4: feature-sliced gather: slice slab per XCD L2. FETCH 195->60 MB.
// R8: pre-scale H by dinv at GEMM output -> agg per-edge work = gather+add.
// R9/R10: 32-feat slices + MFMA gemm (3-term bf16 split): 434us best.
// R11: src-half split via separate dispatches: FETCH 55MB but 2x writes +
//   2x per-dest overhead = regression. R12/R13: subgroup/slice resizing both
//   regressed. MODEL: agg limiter = L2-request count (optimal at 64B rows:
//   E x 4 slices = 6.4M touches) x L2-miss latency (slab 6.4MB > 4MB L2,
//   51% hit). FETCH counts L2-miss traffic (L3-served), hence >> unique.
// R14: R10 geometry unchanged; fix hit rate by (dest, src-half) edge
//   ORDERING only (R11's passC0/passC with mid[], agg reads full range).
//   Waves process lower-half sources (3.2MB working set) then upper-half;
//   phase-coherent L2 -> thrash only in transition window. No extra writes
//   or dispatches. fp32 accum reorder -> absmax may move a hair.
// ---------------------------------------------------------------------------

static inline size_t ws_align(size_t x) { return (x + 255) & ~(size_t)255; }

typedef float __f2 __attribute__((ext_vector_type(2)));
typedef float __f4 __attribute__((ext_vector_type(4)));
typedef __attribute__((ext_vector_type(8))) short short8v;
typedef __attribute__((ext_vector_type(4))) float f32x4;

__device__ __forceinline__ int eidx(const void* p, size_t i, int is64) {
  return is64 ? (int)((const long long*)p)[i] : ((const int*)p)[i];
}

__device__ __forceinline__ uint16_t f2bf(float f) {  // RNE float->bf16
  uint32_t u = __float_as_uint(f);
  u += 0x7fffu + ((u >> 16) & 1u);
  return (uint16_t)(u >> 16);
}
__device__ __forceinline__ float bf_lo(uint32_t h) { return __uint_as_float(h << 16); }
__device__ __forceinline__ float bf_hi(uint32_t h) { return __uint_as_float(h & 0xffff0000u); }

// Detect int64 vs int32 edge_index (little-endian: int64 high words are 0).
__global__ void detect_k(const int* ei, int* flag) {
  if (threadIdx.x == 0 && blockIdx.x == 0) {
    int allz = 1;
    for (int i = 1; i < 128; i += 2)
      if (ei[i] != 0) { allz = 0; break; }
    *flag = allz;
  }
}

// --- passA: bucket histogram via per-block LDS counters --------------------
__global__ __launch_bounds__(256) void passA_k(const void* ei, const int* __restrict__ flag,
                                               int* __restrict__ bucket_cnt, int E, int NB) {
  __shared__ int cnt[256];
  int t = threadIdx.x;
  cnt[t] = 0;
  __syncthreads();
  int is64 = *flag;
  for (int e = blockIdx.x * 256 + t; e < E; e += gridDim.x * 256) {
    int c = eidx(ei, (size_t)E + e, is64);
    atomicAdd(&cnt[c >> 9], 1);
  }
  __syncthreads();
  if (t < NB && cnt[t]) atomicAdd(&bucket_cnt[t], cnt[t]);
}

// --- bscan: exclusive scan of bucket_cnt -> bucket_offs; init gcursor ------
__global__ __launch_bounds__(256) void bscan_k(const int* __restrict__ bucket_cnt,
                                               int* __restrict__ bucket_offs,
                                               int* __restrict__ gcursor, int NB) {
  __shared__ int sh[256];
  int t = threadIdx.x;
  int v = (t < NB) ? bucket_cnt[t] : 0;
  sh[t] = v;
  __syncthreads();
  for (int off = 1; off < 256; off <<= 1) {
    int x = (t >= off) ? sh[t - off] : 0;
    __syncthreads();
    sh[t] += x;
    __syncthreads();
  }
  if (t < NB) {
    int excl = sh[t] - v;
    bucket_offs[t] = excl;
    gcursor[t] = excl;
  }
  if (t == NB - 1) bucket_offs[NB] = sh[t];
}

// --- passB: partition edges into bucket-contiguous epk_binned --------------
__global__ __launch_bounds__(256) void passB_k(const void* ei, const int* __restrict__ flag,
                                               int* __restrict__ gcursor,
                                               int2* __restrict__ epk_binned, int E, int NB) {
  __shared__ int2 sorted[4096];                       // 32 KB
  __shared__ int cnt[256], bbase[256], gb[256], cur[256];
  const int t = threadIdx.x;
  const int base = blockIdx.x * 4096;
  const int CH = min(4096, E - base);
  const int is64 = *flag;

  cnt[t] = 0;
  __syncthreads();
  for (int i = t; i < CH; i += 256) {
    int c = eidx(ei, (size_t)E + base + i, is64);
    atomicAdd(&cnt[c >> 9], 1);
  }
  __syncthreads();
  {
    int v = cnt[t];
    __shared__ int sh[256];
    sh[t] = v;
    __syncthreads();
    for (int off = 1; off < 256; off <<= 1) {
      int x = (t >= off) ? sh[t - off] : 0;
      __syncthreads();
      sh[t] += x;
      __syncthreads();
    }
    bbase[t] = sh[t] - v;
    gb[t] = (t < NB && v) ? atomicAdd(&gcursor[t], v) : 0;
    cur[t] = 0;
  }
  __syncthreads();
  for (int i = t; i < CH; i += 256) {
    int r = eidx(ei, (size_t)base + i, is64);
    int c = eidx(ei, (size_t)E + base + i, is64);
    int b = c >> 9;
    int rank = atomicAdd(&cur[b], 1);
    sorted[bbase[b] + rank] = make_int2(r, c);
  }
  __syncthreads();
  for (int i = t; i < CH; i += 256) {
    int2 v = sorted[i];
    int b = v.y >> 9;
    epk_binned[gb[b] + (i - bbase[b])] = v;
  }
}

// --- passC0: per-(dest,half) counts -> deg[], offs[], mid[] ----------------
__global__ __launch_bounds__(256) void passC0_k(const int2* __restrict__ epk_binned,
                                                const int* __restrict__ bucket_offs,
                                                int* __restrict__ deg, int* __restrict__ offs,
                                                int* __restrict__ mid,
                                                int n, int NB, int NH) {
  __shared__ int dcnt[1024];
  __shared__ int s[256];
  const int t = threadIdx.x;
  const int b = blockIdx.x;
  dcnt[t] = 0; dcnt[t + 256] = 0; dcnt[t + 512] = 0; dcnt[t + 768] = 0;
  __syncthreads();
  const int lo = bucket_offs[b], hi = bucket_offs[b + 1];
  for (int i = lo + t; i < hi; i += 256) {
    int2 v = epk_binned[i];
    int hf = (v.x >= NH) ? 1 : 0;
    atomicAdd(&dcnt[((v.y & 511) << 1) | hf], 1);
  }
  __syncthreads();
  int c00 = dcnt[4 * t], c01 = dcnt[4 * t + 1];
  int c10 = dcnt[4 * t + 2], c11 = dcnt[4 * t + 3];
  int d0 = c00 + c01, d1 = c10 + c11;
  int pv = d0 + d1;
  s[t] = pv;
  __syncthreads();
  for (int off = 1; off < 256; off <<= 1) {
    int x = (t >= off) ? s[t - off] : 0;
    __syncthreads();
    s[t] += x;
    __syncthreads();
  }
  int pex = s[t] - pv;
  const int node0 = b << 9;
  int g0 = node0 + 2 * t, g1 = node0 + 2 * t + 1;
  if (g0 < n) { deg[g0] = d0; offs[g0] = lo + pex; mid[g0] = lo + pex + c00; }
  if (g1 < n) { deg[g1] = d1; offs[g1] = lo + pex + d0; mid[g1] = lo + pex + d0 + c10; }
  if (b == NB - 1 && t == 0) offs[n] = hi;
}

__global__ void dinv_k(const int* __restrict__ deg, float* __restrict__ dinv, int n) {
  int i = blockIdx.x * blockDim.x + threadIdx.x;
  if (i < n) dinv[i] = rsqrtf((float)deg[i] + 1.0f);  // +1 = self loop
}

// --- passC: final placement by (dest, half); entry = plain src -------------
__global__ __launch_bounds__(256) void passC_k(const int2* __restrict__ epk_binned,
                                               const int* __restrict__ bucket_offs,
                                               const int* __restrict__ offs,
                                               const int* __restrict__ mid,
                                               uint32_t* __restrict__ epk, int NH) {
  __shared__ int cur[1024];
  const int t = threadIdx.x;
  const int b = blockIdx.x;
  cur[t] = 0; cur[t + 256] = 0; cur[t + 512] = 0; cur[t + 768] = 0;
  __syncthreads();
  const int lo = bucket_offs[b], hi = bucket_offs[b + 1];
  for (int i = lo + t; i < hi; i += 256) {
    int2 v = epk_binned[i];
    int hf = (v.x >= NH) ? 1 : 0;
    int base = hf ? mid[v.y] : offs[v.y];
    int pos = base + atomicAdd(&cur[((v.y & 511) << 1) | hf], 1);
    epk[pos] = (uint32_t)v.x;
  }
}

// --- wprep: split W fp32 -> bf16 hi/lo MFMA fragments in global ------------
template <int COLS>
__global__ void wprep_k(const float* __restrict__ W, uint16_t* __restrict__ Wf) {
  constexpr int CT = COLS / 16;
  const int f = blockIdx.x;  // [0, 4*CT)
  const int kc = f / CT, ct = f % CT;
  const int l = threadIdx.x;  // 0..63
#pragma unroll
  for (int j = 0; j < 8; ++j) {
    int k = kc * 32 + (l >> 4) * 8 + j;
    int col = ct * 16 + (l & 15);
    float wv = W[(size_t)k * COLS + col];
    uint16_t hi = f2bf(wv);
    float res = wv - __uint_as_float((uint32_t)hi << 16);
    Wf[(size_t)f * 1024 + l * 8 + j] = hi;
    Wf[(size_t)f * 1024 + 512 + l * 8 + j] = f2bf(res);
  }
}

// --- MFMA GEMM: Hs (32-feat-sliced bf16) = dinv[row] * (X @ W) -------------
// X read dense (layer 0) or 32-feat-sliced fp32 (layers 1/2).
template <int COLS, bool SLICED_IN>
__global__ __launch_bounds__(256) void gemm_k(const float* __restrict__ X,
                                              const uint16_t* __restrict__ Wf,
                                              const float* __restrict__ dinv,
                                              uint16_t* __restrict__ H, int N) {
  constexpr int CT = COLS / 16;
  __shared__ uint32_t Xp[128 * 32];  // 16 KB

  const int tid = threadIdx.x;
  const int l = tid & 63, w = tid >> 6;
  const int rowbase = blockIdx.x * 128;
  const float4* X4 = (const float4*)X;

  f32x4 acc[2][CT];
#pragma unroll
  for (int rt = 0; rt < 2; ++rt)
#pragma unroll
    for (int ct = 0; ct < CT; ++ct) acc[rt][ct] = (f32x4)0.f;

  for (int kc = 0; kc < 4; ++kc) {
    __syncthreads();
    // stage X chunk: 128 rows x 32 k, packed bf16 hi/lo, swizzled
#pragma unroll
    for (int t = 0; t < 4; ++t) {
      int i = tid + t * 256;  // 0..1023
      int r = i >> 3, q = i & 7;
      int gr = rowbase + r;
      if (gr >= N) gr = N - 1;
      float4 xv;
      if (SLICED_IN) {
        xv = X4[((size_t)kc * N + gr) * 8 + q];
      } else {
        xv = X4[(size_t)gr * 32 + kc * 8 + q];
      }
      float xs[4] = {xv.x, xv.y, xv.z, xv.w};
      uint32_t p[4];
#pragma unroll
      for (int e = 0; e < 4; ++e) {
        uint16_t hi = f2bf(xs[e]);
        float res = xs[e] - __uint_as_float((uint32_t)hi << 16);
        p[e] = ((uint32_t)hi << 16) | (uint32_t)f2bf(res);
      }
      int blk = q ^ (r & 7);
      *(uint4*)&Xp[r * 32 + blk * 4] = make_uint4(p[0], p[1], p[2], p[3]);
    }
    __syncthreads();

    // A fragments (2 row-tiles), unpack hi/lo via v_perm
    short8v ah[2], al[2];
#pragma unroll
    for (int rt = 0; rt < 2; ++rt) {
      int r = w * 32 + rt * 16 + (l & 15);
      int c = (r & 7) << 2;
      int b0 = ((l >> 4) * 8) ^ c;
      int b1 = ((l >> 4) * 8 + 4) ^ c;
      uint32_t ua[8];
      *(uint4*)&ua[0] = *(const uint4*)&Xp[r * 32 + b0];
      *(uint4*)&ua[4] = *(const uint4*)&Xp[r * 32 + b1];
      union { uint32_t d[4]; short8v v; } ch, cl;
#pragma unroll
      for (int p2 = 0; p2 < 4; ++p2) {
        ch.d[p2] = __builtin_amdgcn_perm(ua[2 * p2 + 1], ua[2 * p2], 0x07060302u);
        cl.d[p2] = __builtin_amdgcn_perm(ua[2 * p2 + 1], ua[2 * p2], 0x05040100u);
      }
      ah[rt] = ch.v;
      al[rt] = cl.v;
    }

    // B fragments from global (L2), 3-term mfma
#pragma unroll
    for (int ct = 0; ct < CT; ++ct) {
      size_t fo = (size_t)(kc * CT + ct) * 1024;
      short8v bh = *(const short8v*)(Wf + fo + l * 8);
      short8v bl = *(const short8v*)(Wf + fo + 512 + l * 8);
#pragma unroll
      for (int rt = 0; rt < 2; ++rt) {
        acc[rt][ct] = __builtin_amdgcn_mfma_f32_16x16x32_bf16(ah[rt], bh, acc[rt][ct], 0, 0, 0);
        acc[rt][ct] = __builtin_amdgcn_mfma_f32_16x16x32_bf16(al[rt], bh, acc[rt][ct], 0, 0, 0);
        acc[rt][ct] = __builtin_amdgcn_mfma_f32_16x16x32_bf16(ah[rt], bl, acc[rt][ct], 0, 0, 0);
      }
    }
  }

  // Epilogue: D col=lane&15, row=(lane>>4)*4+reg. Pair even/odd cols via
  // shfl_xor -> uint32 words, sliced-bf16 H layout (same as agg expects).
  uint32_t* HW = (uint32_t*)H;
  const int lq = l >> 4, lc = l & 15;
#pragma unroll
  for (int rt = 0; rt < 2; ++rt) {
#pragma unroll
    for (int q = 0; q < 4; ++q) {
      int row = rowbase + w * 32 + rt * 16 + lq * 4 + q;
      bool ok = row < N;
      float dv = ok ? dinv[row] : 0.f;
#pragma unroll
      for (int ct = 0; ct < CT; ++ct) {
        float v = acc[rt][ct][q] * dv;
        int b = (int)f2bf(v);
        int other = __shfl_xor(b, 1);
        if (ok && !(l & 1)) {
          uint32_t word = (uint32_t)b | ((uint32_t)other << 16);
          HW[((size_t)(ct >> 1) * N + row) * 16 + (ct & 1) * 8 + (lc >> 1)] = word;
        }
      }
    }
  }
}

// --- Sliced aggregate, 128 feats: 4 slices x 32 feats. slice = blockIdx&3 --
// (XCD = blockIdx%8 -> XCDs {s, s+4} serve slice s.) 8-lane x uint2
// subgroups: full 64B line per (dest,edge) = request-optimal. epk is
// (dest, src-half)-grouped -> lower/upper 3.2MB half-slabs phase through L2.
__global__ __launch_bounds__(256, 8) void agg128s_k(const uint32_t* __restrict__ HW,
                                                    const int* __restrict__ offs,
                                                    const uint32_t* __restrict__ epk,
                                                    const float* __restrict__ bias,
                                                    float* __restrict__ Aout,
                                                    int relu, int N) {
  const int s = blockIdx.x & 3;
  const int g = blockIdx.x >> 2;
  const int lane = threadIdx.x & 63;
  const int wid = threadIdx.x >> 6;
  const int d = lane >> 3, w = lane & 7;
  const int c = g * 32 + wid * 8 + d;
  if (c >= N) return;
  const uint32_t* Hs = HW + (size_t)s * N * 16;
  int e0 = offs[c], e1 = offs[c + 1];
  float a0 = 0.f, a1 = 0.f, a2 = 0.f, a3 = 0.f;
  int e = e0;
  for (; e + 8 <= e1; e += 8) {
    uint32_t p0 = epk[e],     p1 = epk[e + 1], p2 = epk[e + 2], p3 = epk[e + 3];
    uint32_t p4 = epk[e + 4], p5 = epk[e + 5], p6 = epk[e + 6], p7 = epk[e + 7];
    uint2 h0 = *(const uint2*)&Hs[(size_t)p0 * 16 + 2 * w];
    uint2 h1 = *(const uint2*)&Hs[(size_t)p1 * 16 + 2 * w];
    uint2 h2 = *(const uint2*)&Hs[(size_t)p2 * 16 + 2 * w];
    uint2 h3 = *(const uint2*)&Hs[(size_t)p3 * 16 + 2 * w];
    uint2 h4 = *(const uint2*)&Hs[(size_t)p4 * 16 + 2 * w];
    uint2 h5 = *(const uint2*)&Hs[(size_t)p5 * 16 + 2 * w];
    uint2 h6 = *(const uint2*)&Hs[(size_t)p6 * 16 + 2 * w];
    uint2 h7 = *(const uint2*)&Hs[(size_t)p7 * 16 + 2 * w];
    a0 += bf_lo(h0.x); a1 += bf_hi(h0.x); a2 += bf_lo(h0.y); a3 += bf_hi(h0.y);
    a0 += bf_lo(h1.x); a1 += bf_hi(h1.x); a2 += bf_lo(h1.y); a3 += bf_hi(h1.y);
    a0 += bf_lo(h2.x); a1 += bf_hi(h2.x); a2 += bf_lo(h2.y); a3 += bf_hi(h2.y);
    a0 += bf_lo(h3.x); a1 += bf_hi(h3.x); a2 += bf_lo(h3.y); a3 += bf_hi(h3.y);
    a0 += bf_lo(h4.x); a1 += bf_hi(h4.x); a2 += bf_lo(h4.y); a3 += bf_hi(h4.y);
    a0 += bf_lo(h5.x); a1 += bf_hi(h5.x); a2 += bf_lo(h5.y); a3 += bf_hi(h5.y);
    a0 += bf_lo(h6.x); a1 += bf_hi(h6.x); a2 += bf_lo(h6.y); a3 += bf_hi(h6.y);
    a0 += bf_lo(h7.x); a1 += bf_hi(h7.x); a2 += bf_lo(h7.y); a3 += bf_hi(h7.y);
  }
  for (; e + 4 <= e1; e += 4) {
    uint32_t p0 = epk[e], p1 = epk[e + 1], p2 = epk[e + 2], p3 = epk[e + 3];
    uint2 h0 = *(const uint2*)&Hs[(size_t)p0 * 16 + 2 * w];
    uint2 h1 = *(const uint2*)&Hs[(size_t)p1 * 16 + 2 * w];
    uint2 h2 = *(const uint2*)&Hs[(size_t)p2 * 16 + 2 * w];
    uint2 h3 = *(const uint2*)&Hs[(size_t)p3 * 16 + 2 * w];
    a0 += bf_lo(h0.x); a1 += bf_hi(h0.x); a2 += bf_lo(h0.y); a3 += bf_hi(h0.y);
    a0 += bf_lo(h1.x); a1 += bf_hi(h1.x); a2 += bf_lo(h1.y); a3 += bf_hi(h1.y);
    a0 += bf_lo(h2.x); a1 += bf_hi(h2.x); a2 += bf_lo(h2.y); a3 += bf_hi(h2.y);
    a0 += bf_lo(h3.x); a1 += bf_hi(h3.x); a2 += bf_lo(h3.y); a3 += bf_hi(h3.y);
  }
  for (; e < e1; ++e) {
    uint2 h = *(const uint2*)&Hs[(size_t)epk[e] * 16 + 2 * w];
    a0 += bf_lo(h.x); a1 += bf_hi(h.x); a2 += bf_lo(h.y); a3 += bf_hi(h.y);
  }
  float dc = rsqrtf((float)(e1 - e0) + 1.f);
  uint2 hc = *(const uint2*)&Hs[(size_t)c * 16 + 2 * w];
  float r0 = fmaf(dc, a0 + bf_lo(hc.x), bias[s * 32 + 4 * w + 0]);
  float r1 = fmaf(dc, a1 + bf_hi(hc.x), bias[s * 32 + 4 * w + 1]);
  float r2 = fmaf(dc, a2 + bf_lo(hc.y), bias[s * 32 + 4 * w + 2]);
  float r3 = fmaf(dc, a3 + bf_hi(hc.y), bias[s * 32 + 4 * w + 3]);
  if (relu) {
    r0 = fmaxf(r0, 0.f); r1 = fmaxf(r1, 0.f);
    r2 = fmaxf(r2, 0.f); r3 = fmaxf(r3, 0.f);
  }
  __f4 res; res.x = r0; res.y = r1; res.z = r2; res.w = r3;
  __builtin_nontemporal_store(res, (__f4*)(Aout + ((size_t)s * N + c) * 32 + 4 * w));
}

// --- Sliced aggregate, 64 feats: 2 slices x 32 on XCD quads; dense out -----
__global__ __launch_bounds__(256, 8) void agg64s_k(const uint32_t* __restrict__ HW,
                                                   const int* __restrict__ offs,
                                                   const uint32_t* __restrict__ epk,
                                                   const float* __restrict__ bias,
                                                   float* __restrict__ out, int N) {
  const int r = blockIdx.x & 7;
  const int s = r >> 2;          // slice 0..1 (32 feats each)
  const int quar = r & 3;
  const int ng = (N + 31) >> 5;
  const int nq = (ng + 3) >> 2;
  const int g = quar * nq + (blockIdx.x >> 3);
  if (g >= ng) return;
  const int lane = threadIdx.x & 63;
  const int wid = threadIdx.x >> 6;
  const int d = lane >> 3, w = lane & 7;
  const int c = g * 32 + wid * 8 + d;
  if (c >= N) return;
  const uint32_t* Hs = HW + (size_t)s * N * 16;
  int e0 = offs[c], e1 = offs[c + 1];
  float a0 = 0.f, a1 = 0.f, a2 = 0.f, a3 = 0.f;
  int e = e0;
  for (; e + 8 <= e1; e += 8) {
    uint32_t p0 = epk[e],     p1 = epk[e + 1], p2 = epk[e + 2], p3 = epk[e + 3];
    uint32_t p4 = epk[e + 4], p5 = epk[e + 5], p6 = epk[e + 6], p7 = epk[e + 7];
    uint2 h0 = *(const uint2*)&Hs[(size_t)p0 * 16 + 2 * w];
    uint2 h1 = *(const uint2*)&Hs[(size_t)p1 * 16 + 2 * w];
    uint2 h2 = *(const uint2*)&Hs[(size_t)p2 * 16 + 2 * w];
    uint2 h3 = *(const uint2*)&Hs[(size_t)p3 * 16 + 2 * w];
    uint2 h4 = *(const uint2*)&Hs[(size_t)p4 * 16 + 2 * w];
    uint2 h5 = *(const uint2*)&Hs[(size_t)p5 * 16 + 2 * w];
    uint2 h6 = *(const uint2*)&Hs[(size_t)p6 * 16 + 2 * w];
    uint2 h7 = *(const uint2*)&Hs[(size_t)p7 * 16 + 2 * w];
    a0 += bf_lo(h0.x); a1 += bf_hi(h0.x); a2 += bf_lo(h0.y); a3 += bf_hi(h0.y);
    a0 += bf_lo(h1.x); a1 += bf_hi(h1.x); a2 += bf_lo(h1.y); a3 += bf_hi(h1.y);
    a0 += bf_lo(h2.x); a1 += bf_hi(h2.x); a2 += bf_lo(h2.y); a3 += bf_hi(h2.y);
    a0 += bf_lo(h3.x); a1 += bf_hi(h3.x); a2 += bf_lo(h3.y); a3 += bf_hi(h3.y);
    a0 += bf_lo(h4.x); a1 += bf_hi(h4.x); a2 += bf_lo(h4.y); a3 += bf_hi(h4.y);
    a0 += bf_lo(h5.x); a1 += bf_hi(h5.x); a2 += bf_lo(h5.y); a3 += bf_hi(h5.y);
    a0 += bf_lo(h6.x); a1 += bf_hi(h6.x); a2 += bf_lo(h6.y); a3 += bf_hi(h6.y);
    a0 += bf_lo(h7.x); a1 += bf_hi(h7.x); a2 += bf_lo(h7.y); a3 += bf_hi(h7.y);
  }
  for (; e + 4 <= e1; e += 4) {
    uint32_t p0 = epk[e], p1 = epk[e + 1], p2 = epk[e + 2], p3 = epk[e + 3];
    uint2 h0 = *(const uint2*)&Hs[(size_t)p0 * 16 + 2 * w];
    uint2 h1 = *(const uint2*)&Hs[(size_t)p1 * 16 + 2 * w];
    uint2 h2 = *(const uint2*)&Hs[(size_t)p2 * 16 + 2 * w];
    uint2 h3 = *(const uint2*)&Hs[(size_t)p3 * 16 + 2 * w];
    a0 += bf_lo(h0.x); a1 += bf_hi(h0.x); a2 += bf_lo(h0.y); a3 += bf_hi(h0.y);
    a0 += bf_lo(h1.x); a1 += bf_hi(h1.x); a2 += bf_lo(h1.y); a3 += bf_hi(h1.y);
    a0 += bf_lo(h2.x); a1 += bf_hi(h2.x); a2 += bf_lo(h2.y); a3 += bf_hi(h2.y);
    a0 += bf_lo(h3.x); a1 += bf_hi(h3.x); a2 += bf_lo(h3.y); a3 += bf_hi(h3.y);
  }
  for (; e < e1; ++e) {
    uint2 h = *(const uint2*)&Hs[(size_t)epk[e] * 16 + 2 * w];
    a0 += bf_lo(h.x); a1 += bf_hi(h.x); a2 += bf_lo(h.y); a3 += bf_hi(h.y);
  }
  float dc = rsqrtf((float)(e1 - e0) + 1.f);
  uint2 hc = *(const uint2*)&Hs[(size_t)c * 16 + 2 * w];
  float r0 = fmaf(dc, a0 + bf_lo(hc.x), bias[s * 32 + 4 * w + 0]);
  float r1 = fmaf(dc, a1 + bf_hi(hc.x), bias[s * 32 + 4 * w + 1]);
  float r2 = fmaf(dc, a2 + bf_lo(hc.y), bias[s * 32 + 4 * w + 2]);
  float r3 = fmaf(dc, a3 + bf_hi(hc.y), bias[s * 32 + 4 * w + 3]);
  __f4 res; res.x = r0; res.y = r1; res.z = r2; res.w = r3;
  __builtin_nontemporal_store(res, (__f4*)(out + (size_t)c * 64 + s * 32 + 4 * w));
}

extern "C" void kernel_launch(void* const* d_in, const int* in_sizes, int n_in,
                              void* d_out, int out_size, void* d_ws, size_t ws_size,
                              hipStream_t stream) {
  const float* x  = (const float*)d_in[0];
  const void*  ei = d_in[1];
  const float* W0 = (const float*)d_in[2];
  const float* b0 = (const float*)d_in[3];
  const float* W1 = (const float*)d_in[4];
  const float* b1 = (const float*)d_in[5];
  const float* W2 = (const float*)d_in[6];
  const float* b2 = (const float*)d_in[7];
  float* out = (float*)d_out;

  const int n = in_sizes[0] / 128;   // 100000
  const int E = in_sizes[1] / 2;     // 1600000
  const int NB = (n + 511) >> 9;     // buckets of 512 dests (NB <= 256)
  const int NH = n >> 1;             // source half boundary

  char* ws = (char*)d_ws;
  size_t off = 0;
  auto alloc = [&](size_t bytes) { char* p = ws + off; off = ws_align(off + bytes); return p; };
  int*      bucket_cnt  = (int*)alloc(256 * 4);
  int*      bucket_offs = (int*)alloc(257 * 4);
  int*      gcursor     = (int*)alloc(256 * 4);
  int*      deg         = (int*)alloc((size_t)n * 4);
  int*      offs        = (int*)alloc((size_t)(n + 1) * 4);
  int*      mid         = (int*)alloc((size_t)n * 4);
  float*    dinv        = (float*)alloc((size_t)n * 4);
  int*      flag        = (int*)alloc(4);
  uint16_t* wf0         = (uint16_t*)alloc(64 * 1024);
  uint16_t* wf1         = (uint16_t*)alloc(64 * 1024);
  uint16_t* wf2         = (uint16_t*)alloc(32 * 1024);
  int2*     epk_binned  = (int2*)alloc((size_t)E * 8);
  uint32_t* epk         = (uint32_t*)alloc((size_t)E * 4);
  uint16_t* hbuf        = (uint16_t*)alloc((size_t)n * 128 * 2);  // sliced bf16 H'
  float*    abuf        = (float*)alloc((size_t)n * 128 * 4);     // sliced fp32 acts
  (void)ws_size;

  hipMemsetAsync(bucket_cnt, 0, 256 * 4, stream);

  // W split/fragment prep (independent of graph passes)
  wprep_k<128><<<32, 64, 0, stream>>>(W0, wf0);
  wprep_k<128><<<32, 64, 0, stream>>>(W1, wf1);
  wprep_k<64><<<16, 64, 0, stream>>>(W2, wf2);

  detect_k<<<1, 64, 0, stream>>>((const int*)ei, flag);
  passA_k<<<512, 256, 0, stream>>>(ei, flag, bucket_cnt, E, NB);
  bscan_k<<<1, 256, 0, stream>>>(bucket_cnt, bucket_offs, gcursor, NB);
  passB_k<<<(E + 4095) / 4096, 256, 0, stream>>>(ei, flag, gcursor, epk_binned, E, NB);
  passC0_k<<<NB, 256, 0, stream>>>(epk_binned, bucket_offs, deg, offs, mid, n, NB, NH);
  dinv_k<<<(n + 255) / 256, 256, 0, stream>>>(deg, dinv, n);
  passC_k<<<NB, 256, 0, stream>>>(epk_binned, bucket_offs, offs, mid, epk, NH);

  const int gemm_blocks = (n + 127) / 128;
  const int agg128_blocks = 4 * ((n + 31) / 32);
  const int ng = (n + 31) >> 5, nq = (ng + 3) >> 2;
  const int agg64_blocks = 8 * nq;

  // Layer 0 (dense x input)
  gemm_k<128, false><<<gemm_blocks, 256, 0, stream>>>(x, wf0, dinv, hbuf, n);
  agg128s_k<<<agg128_blocks, 256, 0, stream>>>((const uint32_t*)hbuf, offs, epk, b0, abuf, 1, n);
  // Layer 1 (sliced activations)
  gemm_k<128, true><<<gemm_blocks, 256, 0, stream>>>(abuf, wf1, dinv, hbuf, n);
  agg128s_k<<<agg128_blocks, 256, 0, stream>>>((const uint32_t*)hbuf, offs, epk, b1, abuf, 1, n);
  // Layer 2 (no relu) -> d_out dense fp32
  gemm_k<64, true><<<gemm_blocks, 256, 0, stream>>>(abuf, wf2, dinv, hbuf, n);
  agg64s_k<<<agg64_blocks, 256, 0, stream>>>((const uint32_t*)hbuf, offs, epk, b2, out, n);
}

// Round 9
// 424.989 us; speedup vs baseline: 1.1519x; 1.0263x over previous
//
#include <hip/hip_runtime.h>
#include <stdint.h>

// ---------------------------------------------------------------------------
// GCN 3-layer forward:  out = A_hat @ relu(A_hat @ relu(A_hat @ x W0 + b0) W1 + b1) W2 + b2
// A_hat = D^-1/2 (A + I) D^-1/2. With pre-scaled rows h'[r] = dinv[r]*h[r]:
//   out[c] = dinv[c] * ( sum_{edges r->c} h'[r] + h'[c] ) + b
//
// R2: agg FETCH == 8 XCD x sizeof(H) (random graph) -> H stored bf16.
// R3: one-shot scatter was 64B-partial-line bound -> bucketed 2-pass sort.
// R4: feature-sliced gather: slice slab per XCD L2. FETCH 195->60 MB.
// R8: pre-scale H by dinv at GEMM output -> agg per-edge work = gather+add.
// R9/R10: 32-feat slices + MFMA gemm (3-term bf16 split): 434us best.
// R11-R14: agg byte-reduction attempts. MODEL (confirmed x4): agg128 is
//   pinned at E x 4 line-touches (information floor for bf16 256B rows)
//   x ~3.7TB/s random-line service = ~69us. Slab 6.4MB > 4MB L2; only
//   dispatch-level XCD-half binding fixes hit rate and its write/overhead
//   cost loses (R11). Phase-ordering is useless: concurrent blocks mix
//   halves at all times (R14 null). agg structural floor reached.
// R15: attack the ~150us serial prep chain instead (never in top-5 but
//   sums large): passC0/passC 256->1024 threads (NB=196 blocks only -> 4x
//   fewer serial iters, 12 waves/CU), passB 256->512 threads, passA grid
//   1024, detect_k 64-lane ballot. Compute path untouched.
//   (R8 bench: infra failure, resubmitted unchanged.)
// ---------------------------------------------------------------------------

static inline size_t ws_align(size_t x) { return (x + 255) & ~(size_t)255; }

typedef float __f2 __attribute__((ext_vector_type(2)));
typedef float __f4 __attribute__((ext_vector_type(4)));
typedef __attribute__((ext_vector_type(8))) short short8v;
typedef __attribute__((ext_vector_type(4))) float f32x4;

__device__ __forceinline__ int eidx(const void* p, size_t i, int is64) {
  return is64 ? (int)((const long long*)p)[i] : ((const int*)p)[i];
}

__device__ __forceinline__ uint16_t f2bf(float f) {  // RNE float->bf16
  uint32_t u = __float_as_uint(f);
  u += 0x7fffu + ((u >> 16) & 1u);
  return (uint16_t)(u >> 16);
}
__device__ __forceinline__ float bf_lo(uint32_t h) { return __uint_as_float(h << 16); }
__device__ __forceinline__ float bf_hi(uint32_t h) { return __uint_as_float(h & 0xffff0000u); }

// Detect int64 vs int32 edge_index: 64 lanes check high words in parallel.
__global__ void detect_k(const int* ei, int* flag) {
  int l = threadIdx.x;  // 0..63
  int v = ei[2 * l + 1];
  unsigned long long m = __ballot(v == 0);
  if (l == 0) *flag = (m == ~0ULL) ? 1 : 0;
}

// --- passA: bucket histogram via per-block LDS counters --------------------
__global__ __launch_bounds__(256) void passA_k(const void* ei, const int* __restrict__ flag,
                                               int* __restrict__ bucket_cnt, int E, int NB) {
  __shared__ int cnt[256];
  int t = threadIdx.x;
  cnt[t] = 0;
  __syncthreads();
  int is64 = *flag;
  for (int e = blockIdx.x * 256 + t; e < E; e += gridDim.x * 256) {
    int c = eidx(ei, (size_t)E + e, is64);
    atomicAdd(&cnt[c >> 9], 1);
  }
  __syncthreads();
  if (t < NB && cnt[t]) atomicAdd(&bucket_cnt[t], cnt[t]);
}

// --- bscan: exclusive scan of bucket_cnt -> bucket_offs; init gcursor ------
__global__ __launch_bounds__(256) void bscan_k(const int* __restrict__ bucket_cnt,
                                               int* __restrict__ bucket_offs,
                                               int* __restrict__ gcursor, int NB) {
  __shared__ int sh[256];
  int t = threadIdx.x;
  int v = (t < NB) ? bucket_cnt[t] : 0;
  sh[t] = v;
  __syncthreads();
  for (int off = 1; off < 256; off <<= 1) {
    int x = (t >= off) ? sh[t - off] : 0;
    __syncthreads();
    sh[t] += x;
    __syncthreads();
  }
  if (t < NB) {
    int excl = sh[t] - v;
    bucket_offs[t] = excl;
    gcursor[t] = excl;
  }
  if (t == NB - 1) bucket_offs[NB] = sh[t];
}

// --- passB: partition edges into bucket-contiguous epk_binned (512 thr) ----
__global__ __launch_bounds__(512) void passB_k(const void* ei, const int* __restrict__ flag,
                                               int* __restrict__ gcursor,
                                               int2* __restrict__ epk_binned, int E, int NB) {
  __shared__ int2 sorted[4096];                       // 32 KB
  __shared__ int cnt[256], bbase[256], gb[256], cur[256];
  __shared__ int sh[256];
  const int t = threadIdx.x;  // 0..511
  const int base = blockIdx.x * 4096;
  const int CH = min(4096, E - base);
  const int is64 = *flag;

  if (t < 256) cnt[t] = 0;
  __syncthreads();
  for (int i = t; i < CH; i += 512) {
    int c = eidx(ei, (size_t)E + base + i, is64);
    atomicAdd(&cnt[c >> 9], 1);
  }
  __syncthreads();
  if (t < 256) sh[t] = cnt[t];
  __syncthreads();
  for (int off = 1; off < 256; off <<= 1) {
    int x = (t < 256 && t >= off) ? sh[t - off] : 0;
    __syncthreads();
    if (t < 256) sh[t] += x;
    __syncthreads();
  }
  if (t < 256) {
    int v = cnt[t];
    bbase[t] = sh[t] - v;
    gb[t] = (t < NB && v) ? atomicAdd(&gcursor[t], v) : 0;
    cur[t] = 0;
  }
  __syncthreads();
  for (int i = t; i < CH; i += 512) {
    int r = eidx(ei, (size_t)base + i, is64);
    int c = eidx(ei, (size_t)E + base + i, is64);
    int b = c >> 9;
    int rank = atomicAdd(&cur[b], 1);
    sorted[bbase[b] + rank] = make_int2(r, c);
  }
  __syncthreads();
  for (int i = t; i < CH; i += 512) {
    int2 v = sorted[i];
    int b = v.y >> 9;
    epk_binned[gb[b] + (i - bbase[b])] = v;
  }
}

// --- passC0: per-bucket degree count -> deg[], offs[] (1024 threads) -------
__global__ __launch_bounds__(1024) void passC0_k(const int2* __restrict__ epk_binned,
                                                 const int* __restrict__ bucket_offs,
                                                 int* __restrict__ deg, int* __restrict__ offs,
                                                 int n, int NB) {
  __shared__ int dcnt[512];
  __shared__ int s[512];
  const int t = threadIdx.x;  // 0..1023
  const int b = blockIdx.x;
  if (t < 512) dcnt[t] = 0;
  __syncthreads();
  const int lo = bucket_offs[b], hi = bucket_offs[b + 1];
  for (int i = lo + t; i < hi; i += 1024)
    atomicAdd(&dcnt[epk_binned[i].y & 511], 1);
  __syncthreads();
  int v = (t < 512) ? dcnt[t] : 0;
  if (t < 512) s[t] = v;
  __syncthreads();
  for (int off = 1; off < 512; off <<= 1) {
    int x = (t < 512 && t >= off) ? s[t - off] : 0;
    __syncthreads();
    if (t < 512) s[t] += x;
    __syncthreads();
  }
  if (t < 512) {
    int g = (b << 9) + t;
    if (g < n) { deg[g] = v; offs[g] = lo + (s[t] - v); }
  }
  if (b == NB - 1 && t == 0) offs[n] = hi;
}

__global__ void dinv_k(const int* __restrict__ deg, float* __restrict__ dinv, int n) {
  int i = blockIdx.x * blockDim.x + threadIdx.x;
  if (i < n) dinv[i] = rsqrtf((float)deg[i] + 1.0f);  // +1 = self loop
}

// --- passC: final placement by exact dest (1024 threads) -------------------
__global__ __launch_bounds__(1024) void passC_k(const int2* __restrict__ epk_binned,
                                                const int* __restrict__ bucket_offs,
                                                const int* __restrict__ offs,
                                                uint32_t* __restrict__ epk) {
  __shared__ int cur[512];
  const int t = threadIdx.x;  // 0..1023
  const int b = blockIdx.x;
  if (t < 512) cur[t] = 0;
  __syncthreads();
  const int lo = bucket_offs[b], hi = bucket_offs[b + 1];
  for (int i = lo + t; i < hi; i += 1024) {
    int2 v = epk_binned[i];
    int pos = offs[v.y] + atomicAdd(&cur[v.y & 511], 1);
    epk[pos] = (uint32_t)v.x;
  }
}

// --- wprep: split W fp32 -> bf16 hi/lo MFMA fragments in global ------------
template <int COLS>
__global__ void wprep_k(const float* __restrict__ W, uint16_t* __restrict__ Wf) {
  constexpr int CT = COLS / 16;
  const int f = blockIdx.x;  // [0, 4*CT)
  const int kc = f / CT, ct = f % CT;
  const int l = threadIdx.x;  // 0..63
#pragma unroll
  for (int j = 0; j < 8; ++j) {
    int k = kc * 32 + (l >> 4) * 8 + j;
    int col = ct * 16 + (l & 15);
    float wv = W[(size_t)k * COLS + col];
    uint16_t hi = f2bf(wv);
    float res = wv - __uint_as_float((uint32_t)hi << 16);
    Wf[(size_t)f * 1024 + l * 8 + j] = hi;
    Wf[(size_t)f * 1024 + 512 + l * 8 + j] = f2bf(res);
  }
}

// --- MFMA GEMM: Hs (32-feat-sliced bf16) = dinv[row] * (X @ W) -------------
// X read dense (layer 0) or 32-feat-sliced fp32 (layers 1/2).
template <int COLS, bool SLICED_IN>
__global__ __launch_bounds__(256) void gemm_k(const float* __restrict__ X,
                                              const uint16_t* __restrict__ Wf,
                                              const float* __restrict__ dinv,
                                              uint16_t* __restrict__ H, int N) {
  constexpr int CT = COLS / 16;
  __shared__ uint32_t Xp[128 * 32];  // 16 KB

  const int tid = threadIdx.x;
  const int l = tid & 63, w = tid >> 6;
  const int rowbase = blockIdx.x * 128;
  const float4* X4 = (const float4*)X;

  f32x4 acc[2][CT];
#pragma unroll
  for (int rt = 0; rt < 2; ++rt)
#pragma unroll
    for (int ct = 0; ct < CT; ++ct) acc[rt][ct] = (f32x4)0.f;

  for (int kc = 0; kc < 4; ++kc) {
    __syncthreads();
    // stage X chunk: 128 rows x 32 k, packed bf16 hi/lo, swizzled
#pragma unroll
    for (int t = 0; t < 4; ++t) {
      int i = tid + t * 256;  // 0..1023
      int r = i >> 3, q = i & 7;
      int gr = rowbase + r;
      if (gr >= N) gr = N - 1;
      float4 xv;
      if (SLICED_IN) {
        xv = X4[((size_t)kc * N + gr) * 8 + q];
      } else {
        xv = X4[(size_t)gr * 32 + kc * 8 + q];
      }
      float xs[4] = {xv.x, xv.y, xv.z, xv.w};
      uint32_t p[4];
#pragma unroll
      for (int e = 0; e < 4; ++e) {
        uint16_t hi = f2bf(xs[e]);
        float res = xs[e] - __uint_as_float((uint32_t)hi << 16);
        p[e] = ((uint32_t)hi << 16) | (uint32_t)f2bf(res);
      }
      int blk = q ^ (r & 7);
      *(uint4*)&Xp[r * 32 + blk * 4] = make_uint4(p[0], p[1], p[2], p[3]);
    }
    __syncthreads();

    // A fragments (2 row-tiles), unpack hi/lo via v_perm
    short8v ah[2], al[2];
#pragma unroll
    for (int rt = 0; rt < 2; ++rt) {
      int r = w * 32 + rt * 16 + (l & 15);
      int c = (r & 7) << 2;
      int b0 = ((l >> 4) * 8) ^ c;
      int b1 = ((l >> 4) * 8 + 4) ^ c;
      uint32_t ua[8];
      *(uint4*)&ua[0] = *(const uint4*)&Xp[r * 32 + b0];
      *(uint4*)&ua[4] = *(const uint4*)&Xp[r * 32 + b1];
      union { uint32_t d[4]; short8v v; } ch, cl;
#pragma unroll
      for (int p2 = 0; p2 < 4; ++p2) {
        ch.d[p2] = __builtin_amdgcn_perm(ua[2 * p2 + 1], ua[2 * p2], 0x07060302u);
        cl.d[p2] = __builtin_amdgcn_perm(ua[2 * p2 + 1], ua[2 * p2], 0x05040100u);
      }
      ah[rt] = ch.v;
      al[rt] = cl.v;
    }

    // B fragments from global (L2), 3-term mfma
#pragma unroll
    for (int ct = 0; ct < CT; ++ct) {
      size_t fo = (size_t)(kc * CT + ct) * 1024;
      short8v bh = *(const short8v*)(Wf + fo + l * 8);
      short8v bl = *(const short8v*)(Wf + fo + 512 + l * 8);
#pragma unroll
      for (int rt = 0; rt < 2; ++rt) {
        acc[rt][ct] = __builtin_amdgcn_mfma_f32_16x16x32_bf16(ah[rt], bh, acc[rt][ct], 0, 0, 0);
        acc[rt][ct] = __builtin_amdgcn_mfma_f32_16x16x32_bf16(al[rt], bh, acc[rt][ct], 0, 0, 0);
        acc[rt][ct] = __builtin_amdgcn_mfma_f32_16x16x32_bf16(ah[rt], bl, acc[rt][ct], 0, 0, 0);
      }
    }
  }

  // Epilogue: D col=lane&15, row=(lane>>4)*4+reg. Pair even/odd cols via
  // shfl_xor -> uint32 words, sliced-bf16 H layout (same as agg expects).
  uint32_t* HW = (uint32_t*)H;
  const int lq = l >> 4, lc = l & 15;
#pragma unroll
  for (int rt = 0; rt < 2; ++rt) {
#pragma unroll
    for (int q = 0; q < 4; ++q) {
      int row = rowbase + w * 32 + rt * 16 + lq * 4 + q;
      bool ok = row < N;
      float dv = ok ? dinv[row] : 0.f;
#pragma unroll
      for (int ct = 0; ct < CT; ++ct) {
        float v = acc[rt][ct][q] * dv;
        int b = (int)f2bf(v);
        int other = __shfl_xor(b, 1);
        if (ok && !(l & 1)) {
          uint32_t word = (uint32_t)b | ((uint32_t)other << 16);
          HW[((size_t)(ct >> 1) * N + row) * 16 + (ct & 1) * 8 + (lc >> 1)] = word;
        }
      }
    }
  }
}

// --- Sliced aggregate, 128 feats: 4 slices x 32 feats. slice = blockIdx&3 --
// 8-lane x uint2 subgroups: full 64B line per (dest,edge) = request-optimal.
__global__ __launch_bounds__(256, 8) void agg128s_k(const uint32_t* __restrict__ HW,
                                                    const int* __restrict__ offs,
                                                    const uint32_t* __restrict__ epk,
                                                    const float* __restrict__ bias,
                                                    float* __restrict__ Aout,
                                                    int relu, int N) {
  const int s = blockIdx.x & 3;
  const int g = blockIdx.x >> 2;
  const int lane = threadIdx.x & 63;
  const int wid = threadIdx.x >> 6;
  const int d = lane >> 3, w = lane & 7;
  const int c = g * 32 + wid * 8 + d;
  if (c >= N) return;
  const uint32_t* Hs = HW + (size_t)s * N * 16;
  int e0 = offs[c], e1 = offs[c + 1];
  float a0 = 0.f, a1 = 0.f, a2 = 0.f, a3 = 0.f;
  int e = e0;
  for (; e + 8 <= e1; e += 8) {
    uint32_t p0 = epk[e],     p1 = epk[e + 1], p2 = epk[e + 2], p3 = epk[e + 3];
    uint32_t p4 = epk[e + 4], p5 = epk[e + 5], p6 = epk[e + 6], p7 = epk[e + 7];
    uint2 h0 = *(const uint2*)&Hs[(size_t)p0 * 16 + 2 * w];
    uint2 h1 = *(const uint2*)&Hs[(size_t)p1 * 16 + 2 * w];
    uint2 h2 = *(const uint2*)&Hs[(size_t)p2 * 16 + 2 * w];
    uint2 h3 = *(const uint2*)&Hs[(size_t)p3 * 16 + 2 * w];
    uint2 h4 = *(const uint2*)&Hs[(size_t)p4 * 16 + 2 * w];
    uint2 h5 = *(const uint2*)&Hs[(size_t)p5 * 16 + 2 * w];
    uint2 h6 = *(const uint2*)&Hs[(size_t)p6 * 16 + 2 * w];
    uint2 h7 = *(const uint2*)&Hs[(size_t)p7 * 16 + 2 * w];
    a0 += bf_lo(h0.x); a1 += bf_hi(h0.x); a2 += bf_lo(h0.y); a3 += bf_hi(h0.y);
    a0 += bf_lo(h1.x); a1 += bf_hi(h1.x); a2 += bf_lo(h1.y); a3 += bf_hi(h1.y);
    a0 += bf_lo(h2.x); a1 += bf_hi(h2.x); a2 += bf_lo(h2.y); a3 += bf_hi(h2.y);
    a0 += bf_lo(h3.x); a1 += bf_hi(h3.x); a2 += bf_lo(h3.y); a3 += bf_hi(h3.y);
    a0 += bf_lo(h4.x); a1 += bf_hi(h4.x); a2 += bf_lo(h4.y); a3 += bf_hi(h4.y);
    a0 += bf_lo(h5.x); a1 += bf_hi(h5.x); a2 += bf_lo(h5.y); a3 += bf_hi(h5.y);
    a0 += bf_lo(h6.x); a1 += bf_hi(h6.x); a2 += bf_lo(h6.y); a3 += bf_hi(h6.y);
    a0 += bf_lo(h7.x); a1 += bf_hi(h7.x); a2 += bf_lo(h7.y); a3 += bf_hi(h7.y);
  }
  for (; e + 4 <= e1; e += 4) {
    uint32_t p0 = epk[e], p1 = epk[e + 1], p2 = epk[e + 2], p3 = epk[e + 3];
    uint2 h0 = *(const uint2*)&Hs[(size_t)p0 * 16 + 2 * w];
    uint2 h1 = *(const uint2*)&Hs[(size_t)p1 * 16 + 2 * w];
    uint2 h2 = *(const uint2*)&Hs[(size_t)p2 * 16 + 2 * w];
    uint2 h3 = *(const uint2*)&Hs[(size_t)p3 * 16 + 2 * w];
    a0 += bf_lo(h0.x); a1 += bf_hi(h0.x); a2 += bf_lo(h0.y); a3 += bf_hi(h0.y);
    a0 += bf_lo(h1.x); a1 += bf_hi(h1.x); a2 += bf_lo(h1.y); a3 += bf_hi(h1.y);
    a0 += bf_lo(h2.x); a1 += bf_hi(h2.x); a2 += bf_lo(h2.y); a3 += bf_hi(h2.y);
    a0 += bf_lo(h3.x); a1 += bf_hi(h3.x); a2 += bf_lo(h3.y); a3 += bf_hi(h3.y);
  }
  for (; e < e1; ++e) {
    uint2 h = *(const uint2*)&Hs[(size_t)epk[e] * 16 + 2 * w];
    a0 += bf_lo(h.x); a1 += bf_hi(h.x); a2 += bf_lo(h.y); a3 += bf_hi(h.y);
  }
  float dc = rsqrtf((float)(e1 - e0) + 1.f);
  uint2 hc = *(const uint2*)&Hs[(size_t)c * 16 + 2 * w];
  float r0 = fmaf(dc, a0 + bf_lo(hc.x), bias[s * 32 + 4 * w + 0]);
  float r1 = fmaf(dc, a1 + bf_hi(hc.x), bias[s * 32 + 4 * w + 1]);
  float r2 = fmaf(dc, a2 + bf_lo(hc.y), bias[s * 32 + 4 * w + 2]);
  float r3 = fmaf(dc, a3 + bf_hi(hc.y), bias[s * 32 + 4 * w + 3]);
  if (relu) {
    r0 = fmaxf(r0, 0.f); r1 = fmaxf(r1, 0.f);
    r2 = fmaxf(r2, 0.f); r3 = fmaxf(r3, 0.f);
  }
  __f4 res; res.x = r0; res.y = r1; res.z = r2; res.w = r3;
  __builtin_nontemporal_store(res, (__f4*)(Aout + ((size_t)s * N + c) * 32 + 4 * w));
}

// --- Sliced aggregate, 64 feats: 2 slices x 32 on XCD quads; dense out -----
__global__ __launch_bounds__(256, 8) void agg64s_k(const uint32_t* __restrict__ HW,
                                                   const int* __restrict__ offs,
                                                   const uint32_t* __restrict__ epk,
                                                   const float* __restrict__ bias,
                                                   float* __restrict__ out, int N) {
  const int r = blockIdx.x & 7;
  const int s = r >> 2;          // slice 0..1 (32 feats each)
  const int quar = r & 3;
  const int ng = (N + 31) >> 5;
  const int nq = (ng + 3) >> 2;
  const int g = quar * nq + (blockIdx.x >> 3);
  if (g >= ng) return;
  const int lane = threadIdx.x & 63;
  const int wid = threadIdx.x >> 6;
  const int d = lane >> 3, w = lane & 7;
  const int c = g * 32 + wid * 8 + d;
  if (c >= N) return;
  const uint32_t* Hs = HW + (size_t)s * N * 16;
  int e0 = offs[c], e1 = offs[c + 1];
  float a0 = 0.f, a1 = 0.f, a2 = 0.f, a3 = 0.f;
  int e = e0;
  for (; e + 8 <= e1; e += 8) {
    uint32_t p0 = epk[e],     p1 = epk[e + 1], p2 = epk[e + 2], p3 = epk[e + 3];
    uint32_t p4 = epk[e + 4], p5 = epk[e + 5], p6 = epk[e + 6], p7 = epk[e + 7];
    uint2 h0 = *(const uint2*)&Hs[(size_t)p0 * 16 + 2 * w];
    uint2 h1 = *(const uint2*)&Hs[(size_t)p1 * 16 + 2 * w];
    uint2 h2 = *(const uint2*)&Hs[(size_t)p2 * 16 + 2 * w];
    uint2 h3 = *(const uint2*)&Hs[(size_t)p3 * 16 + 2 * w];
    uint2 h4 = *(const uint2*)&Hs[(size_t)p4 * 16 + 2 * w];
    uint2 h5 = *(const uint2*)&Hs[(size_t)p5 * 16 + 2 * w];
    uint2 h6 = *(const uint2*)&Hs[(size_t)p6 * 16 + 2 * w];
    uint2 h7 = *(const uint2*)&Hs[(size_t)p7 * 16 + 2 * w];
    a0 += bf_lo(h0.x); a1 += bf_hi(h0.x); a2 += bf_lo(h0.y); a3 += bf_hi(h0.y);
    a0 += bf_lo(h1.x); a1 += bf_hi(h1.x); a2 += bf_lo(h1.y); a3 += bf_hi(h1.y);
    a0 += bf_lo(h2.x); a1 += bf_hi(h2.x); a2 += bf_lo(h2.y); a3 += bf_hi(h2.y);
    a0 += bf_lo(h3.x); a1 += bf_hi(h3.x); a2 += bf_lo(h3.y); a3 += bf_hi(h3.y);
    a0 += bf_lo(h4.x); a1 += bf_hi(h4.x); a2 += bf_lo(h4.y); a3 += bf_hi(h4.y);
    a0 += bf_lo(h5.x); a1 += bf_hi(h5.x); a2 += bf_lo(h5.y); a3 += bf_hi(h5.y);
    a0 += bf_lo(h6.x); a1 += bf_hi(h6.x); a2 += bf_lo(h6.y); a3 += bf_hi(h6.y);
    a0 += bf_lo(h7.x); a1 += bf_hi(h7.x); a2 += bf_lo(h7.y); a3 += bf_hi(h7.y);
  }
  for (; e + 4 <= e1; e += 4) {
    uint32_t p0 = epk[e], p1 = epk[e + 1], p2 = epk[e + 2], p3 = epk[e + 3];
    uint2 h0 = *(const uint2*)&Hs[(size_t)p0 * 16 + 2 * w];
    uint2 h1 = *(const uint2*)&Hs[(size_t)p1 * 16 + 2 * w];
    uint2 h2 = *(const uint2*)&Hs[(size_t)p2 * 16 + 2 * w];
    uint2 h3 = *(const uint2*)&Hs[(size_t)p3 * 16 + 2 * w];
    a0 += bf_lo(h0.x); a1 += bf_hi(h0.x); a2 += bf_lo(h0.y); a3 += bf_hi(h0.y);
    a0 += bf_lo(h1.x); a1 += bf_hi(h1.x); a2 += bf_lo(h1.y); a3 += bf_hi(h1.y);
    a0 += bf_lo(h2.x); a1 += bf_hi(h2.x); a2 += bf_lo(h2.y); a3 += bf_hi(h2.y);
    a0 += bf_lo(h3.x); a1 += bf_hi(h3.x); a2 += bf_lo(h3.y); a3 += bf_hi(h3.y);
  }
  for (; e < e1; ++e) {
    uint2 h = *(const uint2*)&Hs[(size_t)epk[e] * 16 + 2 * w];
    a0 += bf_lo(h.x); a1 += bf_hi(h.x); a2 += bf_lo(h.y); a3 += bf_hi(h.y);
  }
  float dc = rsqrtf((float)(e1 - e0) + 1.f);
  uint2 hc = *(const uint2*)&Hs[(size_t)c * 16 + 2 * w];
  float r0 = fmaf(dc, a0 + bf_lo(hc.x), bias[s * 32 + 4 * w + 0]);
  float r1 = fmaf(dc, a1 + bf_hi(hc.x), bias[s * 32 + 4 * w + 1]);
  float r2 = fmaf(dc, a2 + bf_lo(hc.y), bias[s * 32 + 4 * w + 2]);
  float r3 = fmaf(dc, a3 + bf_hi(hc.y), bias[s * 32 + 4 * w + 3]);
  __f4 res; res.x = r0; res.y = r1; res.z = r2; res.w = r3;
  __builtin_nontemporal_store(res, (__f4*)(out + (size_t)c * 64 + s * 32 + 4 * w));
}

extern "C" void kernel_launch(void* const* d_in, const int* in_sizes, int n_in,
                              void* d_out, int out_size, void* d_ws, size_t ws_size,
                              hipStream_t stream) {
  const float* x  = (const float*)d_in[0];
  const void*  ei = d_in[1];
  const float* W0 = (const float*)d_in[2];
  const float* b0 = (const float*)d_in[3];
  const float* W1 = (const float*)d_in[4];
  const float* b1 = (const float*)d_in[5];
  const float* W2 = (const float*)d_in[6];
  const float* b2 = (const float*)d_in[7];
  float* out = (float*)d_out;

  const int n = in_sizes[0] / 128;   // 100000
  const int E = in_sizes[1] / 2;     // 1600000
  const int NB = (n + 511) >> 9;     // buckets of 512 dests (NB <= 256)

  char* ws = (char*)d_ws;
  size_t off = 0;
  auto alloc = [&](size_t bytes) { char* p = ws + off; off = ws_align(off + bytes); return p; };
  int*      bucket_cnt  = (int*)alloc(256 * 4);
  int*      bucket_offs = (int*)alloc(257 * 4);
  int*      gcursor     = (int*)alloc(256 * 4);
  int*      deg         = (int*)alloc((size_t)n * 4);
  int*      offs        = (int*)alloc((size_t)(n + 1) * 4);
  float*    dinv        = (float*)alloc((size_t)n * 4);
  int*      flag        = (int*)alloc(4);
  uint16_t* wf0         = (uint16_t*)alloc(64 * 1024);
  uint16_t* wf1         = (uint16_t*)alloc(64 * 1024);
  uint16_t* wf2         = (uint16_t*)alloc(32 * 1024);
  int2*     epk_binned  = (int2*)alloc((size_t)E * 8);
  uint32_t* epk         = (uint32_t*)alloc((size_t)E * 4);
  uint16_t* hbuf        = (uint16_t*)alloc((size_t)n * 128 * 2);  // sliced bf16 H'
  float*    abuf        = (float*)alloc((size_t)n * 128 * 4);     // sliced fp32 acts
  (void)ws_size;

  hipMemsetAsync(bucket_cnt, 0, 256 * 4, stream);

  // W split/fragment prep (independent of graph passes)
  wprep_k<128><<<32, 64, 0, stream>>>(W0, wf0);
  wprep_k<128><<<32, 64, 0, stream>>>(W1, wf1);
  wprep_k<64><<<16, 64, 0, stream>>>(W2, wf2);

  detect_k<<<1, 64, 0, stream>>>((const int*)ei, flag);
  passA_k<<<1024, 256, 0, stream>>>(ei, flag, bucket_cnt, E, NB);
  bscan_k<<<1, 256, 0, stream>>>(bucket_cnt, bucket_offs, gcursor, NB);
  passB_k<<<(E + 4095) / 4096, 512, 0, stream>>>(ei, flag, gcursor, epk_binned, E, NB);
  passC0_k<<<NB, 1024, 0, stream>>>(epk_binned, bucket_offs, deg, offs, n, NB);
  dinv_k<<<(n + 255) / 256, 256, 0, stream>>>(deg, dinv, n);
  passC_k<<<NB, 1024, 0, stream>>>(epk_binned, bucket_offs, offs, epk);

  const int gemm_blocks = (n + 127) / 128;
  const int agg128_blocks = 4 * ((n + 31) / 32);
  const int ng = (n + 31) >> 5, nq = (ng + 3) >> 2;
  const int agg64_blocks = 8 * nq;

  // Layer 0 (dense x input)
  gemm_k<128, false><<<gemm_blocks, 256, 0, stream>>>(x, wf0, dinv, hbuf, n);
  agg128s_k<<<agg128_blocks, 256, 0, stream>>>((const uint32_t*)hbuf, offs, epk, b0, abuf, 1, n);
  // Layer 1 (sliced activations)
  gemm_k<128, true><<<gemm_blocks, 256, 0, stream>>>(abuf, wf1, dinv, hbuf, n);
  agg128s_k<<<agg128_blocks, 256, 0, stream>>>((const uint32_t*)hbuf, offs, epk, b1, abuf, 1, n);
  // Layer 2 (no relu) -> d_out dense fp32
  gemm_k<64, true><<<gemm_blocks, 256, 0, stream>>>(abuf, wf2, dinv, hbuf, n);
  agg64s_k<<<agg64_blocks, 256, 0, stream>>>((const uint32_t*)hbuf, offs, epk, b2, out, n);
}

// Round 10
// 418.490 us; speedup vs baseline: 1.1698x; 1.0155x over previous
//
#include <hip/hip_runtime.h>
#include <stdint.h>

// ---------------------------------------------------------------------------
// GCN 3-layer forward:  out = A_hat @ relu(A_hat @ relu(A_hat @ x W0 + b0) W1 + b1) W2 + b2
// A_hat = D^-1/2 (A + I) D^-1/2. With pre-scaled rows h'[r] = dinv[r]*h[r]:
//   out[c] = dinv[c] * ( sum_{edges r->c} h'[r] + h'[c] ) + b
//
// R2-R10: bf16 H, bucketed 2-pass edge sort, 32-feat slices (slab/XCD),
//   MFMA gemm w/ 3-term bf16 split, pre-scale by dinv. 434us.
// R11-R14: agg byte-reduction attempts all null/regressed. MODEL (x5): agg128
//   pinned at E x 4 line-touches x ~3.7TB/s L2-miss service = ~69us. Slab
//   6.4MB > 4MB L2; only dispatch-level XCD-half binding cuts misses and its
//   overhead loses (R11). agg gather side is at structural floor.
// R15: prep chain widened (passB 512thr, passC0/C 1024thr): 436->425.
// R16: cut non-floor bytes. (a) activations stored bf16: agg128 WRITE
//   50->25MB (dur ~61us), gemm L1/L2 X-read halves; (b) bf16 input is
//   EXACT -> lo-residual = 0 -> 2-term MFMA + trivial staging for L1/L2;
//   (c) epk_binned packed uint32 (src17|dloc9): prep -38MB, passB LDS 21KB.
//   absmax may rise ~2-3x (one extra bf16 rounding at acts). Pre-commit:
//   if accuracy fails, revert (a) and declare 425 the floor.
// ---------------------------------------------------------------------------

static inline size_t ws_align(size_t x) { return (x + 255) & ~(size_t)255; }

typedef float __f2 __attribute__((ext_vector_type(2)));
typedef float __f4 __attribute__((ext_vector_type(4)));
typedef uint32_t __u2 __attribute__((ext_vector_type(2)));
typedef __attribute__((ext_vector_type(8))) short short8v;
typedef __attribute__((ext_vector_type(4))) float f32x4;

__device__ __forceinline__ int eidx(const void* p, size_t i, int is64) {
  return is64 ? (int)((const long long*)p)[i] : ((const int*)p)[i];
}

__device__ __forceinline__ uint16_t f2bf(float f) {  // RNE float->bf16
  uint32_t u = __float_as_uint(f);
  u += 0x7fffu + ((u >> 16) & 1u);
  return (uint16_t)(u >> 16);
}
__device__ __forceinline__ float bf_lo(uint32_t h) { return __uint_as_float(h << 16); }
__device__ __forceinline__ float bf_hi(uint32_t h) { return __uint_as_float(h & 0xffff0000u); }

// Detect int64 vs int32 edge_index: 64 lanes check high words in parallel.
__global__ void detect_k(const int* ei, int* flag) {
  int l = threadIdx.x;  // 0..63
  int v = ei[2 * l + 1];
  unsigned long long m = __ballot(v == 0);
  if (l == 0) *flag = (m == ~0ULL) ? 1 : 0;
}

// --- passA: bucket histogram via per-block LDS counters --------------------
__global__ __launch_bounds__(256) void passA_k(const void* ei, const int* __restrict__ flag,
                                               int* __restrict__ bucket_cnt, int E, int NB) {
  __shared__ int cnt[256];
  int t = threadIdx.x;
  cnt[t] = 0;
  __syncthreads();
  int is64 = *flag;
  for (int e = blockIdx.x * 256 + t; e < E; e += gridDim.x * 256) {
    int c = eidx(ei, (size_t)E + e, is64);
    atomicAdd(&cnt[c >> 9], 1);
  }
  __syncthreads();
  if (t < NB && cnt[t]) atomicAdd(&bucket_cnt[t], cnt[t]);
}

// --- bscan: exclusive scan of bucket_cnt -> bucket_offs; init gcursor ------
__global__ __launch_bounds__(256) void bscan_k(const int* __restrict__ bucket_cnt,
                                               int* __restrict__ bucket_offs,
                                               int* __restrict__ gcursor, int NB) {
  __shared__ int sh[256];
  int t = threadIdx.x;
  int v = (t < NB) ? bucket_cnt[t] : 0;
  sh[t] = v;
  __syncthreads();
  for (int off = 1; off < 256; off <<= 1) {
    int x = (t >= off) ? sh[t - off] : 0;
    __syncthreads();
    sh[t] += x;
    __syncthreads();
  }
  if (t < NB) {
    int excl = sh[t] - v;
    bucket_offs[t] = excl;
    gcursor[t] = excl;
  }
  if (t == NB - 1) bucket_offs[NB] = sh[t];
}

// --- passB: partition edges into bucket-contiguous packed entries ----------
// Entry = (src << 9) | (dest & 511). Bucket implied by position.
__global__ __launch_bounds__(512) void passB_k(const void* ei, const int* __restrict__ flag,
                                               int* __restrict__ gcursor,
                                               uint32_t* __restrict__ epk_binned, int E, int NB) {
  __shared__ uint32_t sorted[4096];                   // 16 KB
  __shared__ int cnt[256], bbase[256], gb[256], cur[256];
  __shared__ int sh[256];
  const int t = threadIdx.x;  // 0..511
  const int base = blockIdx.x * 4096;
  const int CH = min(4096, E - base);
  const int is64 = *flag;

  if (t < 256) cnt[t] = 0;
  __syncthreads();
  for (int i = t; i < CH; i += 512) {
    int c = eidx(ei, (size_t)E + base + i, is64);
    atomicAdd(&cnt[c >> 9], 1);
  }
  __syncthreads();
  if (t < 256) sh[t] = cnt[t];
  __syncthreads();
  for (int off = 1; off < 256; off <<= 1) {
    int x = (t < 256 && t >= off) ? sh[t - off] : 0;
    __syncthreads();
    if (t < 256) sh[t] += x;
    __syncthreads();
  }
  if (t < 256) {
    int v = cnt[t];
    bbase[t] = sh[t] - v;
    gb[t] = (t < NB && v) ? atomicAdd(&gcursor[t], v) : 0;
    cur[t] = 0;
  }
  __syncthreads();
  for (int i = t; i < CH; i += 512) {
    int r = eidx(ei, (size_t)base + i, is64);
    int c = eidx(ei, (size_t)E + base + i, is64);
    int b = c >> 9;
    int rank = atomicAdd(&cur[b], 1);
    sorted[bbase[b] + rank] = ((uint32_t)r << 9) | (uint32_t)(c & 511);
  }
  __syncthreads();
  // recompute bucket of each sorted slot via bbase boundaries: use cnt scan.
  // Simpler: each slot's bucket = index of bbase range; store bucket in high
  // pass: iterate and binary-search is overkill -> recover from position:
  for (int i = t; i < CH; i += 512) {
    // find bucket b such that bbase[b] <= i < bbase[b]+cnt[b] -- instead of
    // search, re-read the packed dest-local and we only need bucket for the
    // global write offset; recover it by comparing with bbase via the dest
    // stored at sort time is local, so carry bucket separately:
    // (we re-derive bucket from the ORIGINAL edge like before)
    // NOTE: positions in `sorted` are bucket-contiguous; bucket of slot i is
    // found from the monotone bbase array via linear scan in registers is
    // too slow; instead store bucket in bits [31:26]? NB<=256 needs 8 bits;
    // 17+9+8 = 34 > 32. So: recompute via second pass over edges:
    ;
  }
  // Write out: iterate edges again (global-ordered), but we must write each
  // sorted slot once. Use the same loop as sort: for each edge we know its
  // slot (bbase[b]+rank) but rank was consumed. Instead: iterate slots per
  // bucket using cnt/bbase (each thread walks buckets strided):
  for (int b = t; b < 256; b += 512) {
    int lo = bbase[b], c0 = cnt[b], g0 = gb[b];
    for (int j = 0; j < c0; ++j)
      epk_binned[g0 + j] = sorted[lo + j];
  }
}

// --- passC0: per-bucket degree count -> deg[], offs[] (1024 threads) -------
__global__ __launch_bounds__(1024) void passC0_k(const uint32_t* __restrict__ epk_binned,
                                                 const int* __restrict__ bucket_offs,
                                                 int* __restrict__ deg, int* __restrict__ offs,
                                                 int n, int NB) {
  __shared__ int dcnt[512];
  __shared__ int s[512];
  const int t = threadIdx.x;  // 0..1023
  const int b = blockIdx.x;
  if (t < 512) dcnt[t] = 0;
  __syncthreads();
  const int lo = bucket_offs[b], hi = bucket_offs[b + 1];
  for (int i = lo + t; i < hi; i += 1024)
    atomicAdd(&dcnt[epk_binned[i] & 511u], 1);
  __syncthreads();
  int v = (t < 512) ? dcnt[t] : 0;
  if (t < 512) s[t] = v;
  __syncthreads();
  for (int off = 1; off < 512; off <<= 1) {
    int x = (t < 512 && t >= off) ? s[t - off] : 0;
    __syncthreads();
    if (t < 512) s[t] += x;
    __syncthreads();
  }
  if (t < 512) {
    int g = (b << 9) + t;
    if (g < n) { deg[g] = v; offs[g] = lo + (s[t] - v); }
  }
  if (b == NB - 1 && t == 0) offs[n] = hi;
}

__global__ void dinv_k(const int* __restrict__ deg, float* __restrict__ dinv, int n) {
  int i = blockIdx.x * blockDim.x + threadIdx.x;
  if (i < n) dinv[i] = rsqrtf((float)deg[i] + 1.0f);  // +1 = self loop
}

// --- passC: final placement by exact dest (1024 threads) -------------------
__global__ __launch_bounds__(1024) void passC_k(const uint32_t* __restrict__ epk_binned,
                                                const int* __restrict__ bucket_offs,
                                                const int* __restrict__ offs,
                                                uint32_t* __restrict__ epk) {
  __shared__ int cur[512];
  const int t = threadIdx.x;  // 0..1023
  const int b = blockIdx.x;
  if (t < 512) cur[t] = 0;
  __syncthreads();
  const int lo = bucket_offs[b], hi = bucket_offs[b + 1];
  const int node0 = b << 9;
  for (int i = lo + t; i < hi; i += 1024) {
    uint32_t v = epk_binned[i];
    int dl = (int)(v & 511u);
    int pos = offs[node0 + dl] + atomicAdd(&cur[dl], 1);
    epk[pos] = v >> 9;
  }
}

// --- wprep: split W fp32 -> bf16 hi/lo MFMA fragments in global ------------
template <int COLS>
__global__ void wprep_k(const float* __restrict__ W, uint16_t* __restrict__ Wf) {
  constexpr int CT = COLS / 16;
  const int f = blockIdx.x;  // [0, 4*CT)
  const int kc = f / CT, ct = f % CT;
  const int l = threadIdx.x;  // 0..63
#pragma unroll
  for (int j = 0; j < 8; ++j) {
    int k = kc * 32 + (l >> 4) * 8 + j;
    int col = ct * 16 + (l & 15);
    float wv = W[(size_t)k * COLS + col];
    uint16_t hi = f2bf(wv);
    float res = wv - __uint_as_float((uint32_t)hi << 16);
    Wf[(size_t)f * 1024 + l * 8 + j] = hi;
    Wf[(size_t)f * 1024 + 512 + l * 8 + j] = f2bf(res);
  }
}

// --- MFMA GEMM: Hs (32-feat-sliced bf16) = dinv[row] * (X @ W) -------------
// Layer 0: X dense fp32, 3-term split (Ah*Bh + Al*Bh + Ah*Bl).
// Layers 1/2 (SLICED_IN): X is 32-feat-sliced bf16 (exact) -> Al = 0 ->
//   2-term (Ah*Bh + Ah*Bl), staging = shift/mask only.
template <int COLS, bool SLICED_IN>
__global__ __launch_bounds__(256) void gemm_k(const void* __restrict__ Xv,
                                              const uint16_t* __restrict__ Wf,
                                              const float* __restrict__ dinv,
                                              uint16_t* __restrict__ H, int N) {
  constexpr int CT = COLS / 16;
  __shared__ uint32_t Xp[128 * 32];  // 16 KB

  const int tid = threadIdx.x;
  const int l = tid & 63, w = tid >> 6;
  const int rowbase = blockIdx.x * 128;

  f32x4 acc[2][CT];
#pragma unroll
  for (int rt = 0; rt < 2; ++rt)
#pragma unroll
    for (int ct = 0; ct < CT; ++ct) acc[rt][ct] = (f32x4)0.f;

  for (int kc = 0; kc < 4; ++kc) {
    __syncthreads();
    // stage X chunk: 128 rows x 32 k, packed (hi<<16|lo) uint32, swizzled
#pragma unroll
    for (int t = 0; t < 4; ++t) {
      int i = tid + t * 256;  // 0..1023
      int r = i >> 3, q = i & 7;
      int gr = rowbase + r;
      if (gr >= N) gr = N - 1;
      uint32_t p[4];
      if (SLICED_IN) {
        const uint32_t* XW = (const uint32_t*)Xv;
        uint2 wv = *(const uint2*)&XW[((size_t)kc * N + gr) * 16 + 2 * q];
        p[0] = wv.x << 16;
        p[1] = wv.x & 0xffff0000u;
        p[2] = wv.y << 16;
        p[3] = wv.y & 0xffff0000u;
      } else {
        const float4* X4 = (const float4*)Xv;
        float4 xv = X4[(size_t)gr * 32 + kc * 8 + q];
        float xs[4] = {xv.x, xv.y, xv.z, xv.w};
#pragma unroll
        for (int e = 0; e < 4; ++e) {
          uint16_t hi = f2bf(xs[e]);
          float res = xs[e] - __uint_as_float((uint32_t)hi << 16);
          p[e] = ((uint32_t)hi << 16) | (uint32_t)f2bf(res);
        }
      }
      int blk = q ^ (r & 7);
      *(uint4*)&Xp[r * 32 + blk * 4] = make_uint4(p[0], p[1], p[2], p[3]);
    }
    __syncthreads();

    // A fragments (2 row-tiles), unpack hi/lo via v_perm
    short8v ah[2], al[2];
#pragma unroll
    for (int rt = 0; rt < 2; ++rt) {
      int r = w * 32 + rt * 16 + (l & 15);
      int c = (r & 7) << 2;
      int b0 = ((l >> 4) * 8) ^ c;
      int b1 = ((l >> 4) * 8 + 4) ^ c;
      uint32_t ua[8];
      *(uint4*)&ua[0] = *(const uint4*)&Xp[r * 32 + b0];
      *(uint4*)&ua[4] = *(const uint4*)&Xp[r * 32 + b1];
      union { uint32_t d[4]; short8v v; } ch, cl;
#pragma unroll
      for (int p2 = 0; p2 < 4; ++p2) {
        ch.d[p2] = __builtin_amdgcn_perm(ua[2 * p2 + 1], ua[2 * p2], 0x07060302u);
        if (!SLICED_IN)
          cl.d[p2] = __builtin_amdgcn_perm(ua[2 * p2 + 1], ua[2 * p2], 0x05040100u);
      }
      ah[rt] = ch.v;
      if (!SLICED_IN) al[rt] = cl.v;
    }

    // B fragments from global (L2)
#pragma unroll
    for (int ct = 0; ct < CT; ++ct) {
      size_t fo = (size_t)(kc * CT + ct) * 1024;
      short8v bh = *(const short8v*)(Wf + fo + l * 8);
      short8v bl = *(const short8v*)(Wf + fo + 512 + l * 8);
#pragma unroll
      for (int rt = 0; rt < 2; ++rt) {
        acc[rt][ct] = __builtin_amdgcn_mfma_f32_16x16x32_bf16(ah[rt], bh, acc[rt][ct], 0, 0, 0);
        if (!SLICED_IN)
          acc[rt][ct] = __builtin_amdgcn_mfma_f32_16x16x32_bf16(al[rt], bh, acc[rt][ct], 0, 0, 0);
        acc[rt][ct] = __builtin_amdgcn_mfma_f32_16x16x32_bf16(ah[rt], bl, acc[rt][ct], 0, 0, 0);
      }
    }
  }

  // Epilogue: D col=lane&15, row=(lane>>4)*4+reg. Pair even/odd cols via
  // shfl_xor -> uint32 words, sliced-bf16 H layout (same as agg expects).
  uint32_t* HW = (uint32_t*)H;
  const int lq = l >> 4, lc = l & 15;
#pragma unroll
  for (int rt = 0; rt < 2; ++rt) {
#pragma unroll
    for (int q = 0; q < 4; ++q) {
      int row = rowbase + w * 32 + rt * 16 + lq * 4 + q;
      bool ok = row < N;
      float dv = ok ? dinv[row] : 0.f;
#pragma unroll
      for (int ct = 0; ct < CT; ++ct) {
        float v = acc[rt][ct][q] * dv;
        int b = (int)f2bf(v);
        int other = __shfl_xor(b, 1);
        if (ok && !(l & 1)) {
          uint32_t word = (uint32_t)b | ((uint32_t)other << 16);
          HW[((size_t)(ct >> 1) * N + row) * 16 + (ct & 1) * 8 + (lc >> 1)] = word;
        }
      }
    }
  }
}

// --- Sliced aggregate, 128 feats: 4 slices x 32 feats. slice = blockIdx&3 --
// 8-lane x uint2 subgroups; bf16 OUTPUT (uint2 of 2 packed words per lane).
__global__ __launch_bounds__(256, 8) void agg128s_k(const uint32_t* __restrict__ HW,
                                                    const int* __restrict__ offs,
                                                    const uint32_t* __restrict__ epk,
                                                    const float* __restrict__ bias,
                                                    uint32_t* __restrict__ Aout,
                                                    int relu, int N) {
  const int s = blockIdx.x & 3;
  const int g = blockIdx.x >> 2;
  const int lane = threadIdx.x & 63;
  const int wid = threadIdx.x >> 6;
  const int d = lane >> 3, w = lane & 7;
  const int c = g * 32 + wid * 8 + d;
  if (c >= N) return;
  const uint32_t* Hs = HW + (size_t)s * N * 16;
  int e0 = offs[c], e1 = offs[c + 1];
  float a0 = 0.f, a1 = 0.f, a2 = 0.f, a3 = 0.f;
  int e = e0;
  for (; e + 8 <= e1; e += 8) {
    uint32_t p0 = epk[e],     p1 = epk[e + 1], p2 = epk[e + 2], p3 = epk[e + 3];
    uint32_t p4 = epk[e + 4], p5 = epk[e + 5], p6 = epk[e + 6], p7 = epk[e + 7];
    uint2 h0 = *(const uint2*)&Hs[(size_t)p0 * 16 + 2 * w];
    uint2 h1 = *(const uint2*)&Hs[(size_t)p1 * 16 + 2 * w];
    uint2 h2 = *(const uint2*)&Hs[(size_t)p2 * 16 + 2 * w];
    uint2 h3 = *(const uint2*)&Hs[(size_t)p3 * 16 + 2 * w];
    uint2 h4 = *(const uint2*)&Hs[(size_t)p4 * 16 + 2 * w];
    uint2 h5 = *(const uint2*)&Hs[(size_t)p5 * 16 + 2 * w];
    uint2 h6 = *(const uint2*)&Hs[(size_t)p6 * 16 + 2 * w];
    uint2 h7 = *(const uint2*)&Hs[(size_t)p7 * 16 + 2 * w];
    a0 += bf_lo(h0.x); a1 += bf_hi(h0.x); a2 += bf_lo(h0.y); a3 += bf_hi(h0.y);
    a0 += bf_lo(h1.x); a1 += bf_hi(h1.x); a2 += bf_lo(h1.y); a3 += bf_hi(h1.y);
    a0 += bf_lo(h2.x); a1 += bf_hi(h2.x); a2 += bf_lo(h2.y); a3 += bf_hi(h2.y);
    a0 += bf_lo(h3.x); a1 += bf_hi(h3.x); a2 += bf_lo(h3.y); a3 += bf_hi(h3.y);
    a0 += bf_lo(h4.x); a1 += bf_hi(h4.x); a2 += bf_lo(h4.y); a3 += bf_hi(h4.y);
    a0 += bf_lo(h5.x); a1 += bf_hi(h5.x); a2 += bf_lo(h5.y); a3 += bf_hi(h5.y);
    a0 += bf_lo(h6.x); a1 += bf_hi(h6.x); a2 += bf_lo(h6.y); a3 += bf_hi(h6.y);
    a0 += bf_lo(h7.x); a1 += bf_hi(h7.x); a2 += bf_lo(h7.y); a3 += bf_hi(h7.y);
  }
  for (; e + 4 <= e1; e += 4) {
    uint32_t p0 = epk[e], p1 = epk[e + 1], p2 = epk[e + 2], p3 = epk[e + 3];
    uint2 h0 = *(const uint2*)&Hs[(size_t)p0 * 16 + 2 * w];
    uint2 h1 = *(const uint2*)&Hs[(size_t)p1 * 16 + 2 * w];
    uint2 h2 = *(const uint2*)&Hs[(size_t)p2 * 16 + 2 * w];
    uint2 h3 = *(const uint2*)&Hs[(size_t)p3 * 16 + 2 * w];
    a0 += bf_lo(h0.x); a1 += bf_hi(h0.x); a2 += bf_lo(h0.y); a3 += bf_hi(h0.y);
    a0 += bf_lo(h1.x); a1 += bf_hi(h1.x); a2 += bf_lo(h1.y); a3 += bf_hi(h1.y);
    a0 += bf_lo(h2.x); a1 += bf_hi(h2.x); a2 += bf_lo(h2.y); a3 += bf_hi(h2.y);
    a0 += bf_lo(h3.x); a1 += bf_hi(h3.x); a2 += bf_lo(h3.y); a3 += bf_hi(h3.y);
  }
  for (; e < e1; ++e) {
    uint2 h = *(const uint2*)&Hs[(size_t)epk[e] * 16 + 2 * w];
    a0 += bf_lo(h.x); a1 += bf_hi(h.x); a2 += bf_lo(h.y); a3 += bf_hi(h.y);
  }
  float dc = rsqrtf((float)(e1 - e0) + 1.f);
  uint2 hc = *(const uint2*)&Hs[(size_t)c * 16 + 2 * w];
  float r0 = fmaf(dc, a0 + bf_lo(hc.x), bias[s * 32 + 4 * w + 0]);
  float r1 = fmaf(dc, a1 + bf_hi(hc.x), bias[s * 32 + 4 * w + 1]);
  float r2 = fmaf(dc, a2 + bf_lo(hc.y), bias[s * 32 + 4 * w + 2]);
  float r3 = fmaf(dc, a3 + bf_hi(hc.y), bias[s * 32 + 4 * w + 3]);
  if (relu) {
    r0 = fmaxf(r0, 0.f); r1 = fmaxf(r1, 0.f);
    r2 = fmaxf(r2, 0.f); r3 = fmaxf(r3, 0.f);
  }
  uint32_t w0 = (uint32_t)f2bf(r0) | ((uint32_t)f2bf(r1) << 16);
  uint32_t w1 = (uint32_t)f2bf(r2) | ((uint32_t)f2bf(r3) << 16);
  __u2 res; res.x = w0; res.y = w1;
  __builtin_nontemporal_store(res, (__u2*)(Aout + ((size_t)s * N + c) * 16 + 2 * w));
}

// --- Sliced aggregate, 64 feats: 2 slices x 32 on XCD quads; fp32 out ------
__global__ __launch_bounds__(256, 8) void agg64s_k(const uint32_t* __restrict__ HW,
                                                   const int* __restrict__ offs,
                                                   const uint32_t* __restrict__ epk,
                                                   const float* __restrict__ bias,
                                                   float* __restrict__ out, int N) {
  const int r = blockIdx.x & 7;
  const int s = r >> 2;          // slice 0..1 (32 feats each)
  const int quar = r & 3;
  const int ng = (N + 31) >> 5;
  const int nq = (ng + 3) >> 2;
  const int g = quar * nq + (blockIdx.x >> 3);
  if (g >= ng) return;
  const int lane = threadIdx.x & 63;
  const int wid = threadIdx.x >> 6;
  const int d = lane >> 3, w = lane & 7;
  const int c = g * 32 + wid * 8 + d;
  if (c >= N) return;
  const uint32_t* Hs = HW + (size_t)s * N * 16;
  int e0 = offs[c], e1 = offs[c + 1];
  float a0 = 0.f, a1 = 0.f, a2 = 0.f, a3 = 0.f;
  int e = e0;
  for (; e + 8 <= e1; e += 8) {
    uint32_t p0 = epk[e],     p1 = epk[e + 1], p2 = epk[e + 2], p3 = epk[e + 3];
    uint32_t p4 = epk[e + 4], p5 = epk[e + 5], p6 = epk[e + 6], p7 = epk[e + 7];
    uint2 h0 = *(const uint2*)&Hs[(size_t)p0 * 16 + 2 * w];
    uint2 h1 = *(const uint2*)&Hs[(size_t)p1 * 16 + 2 * w];
    uint2 h2 = *(const uint2*)&Hs[(size_t)p2 * 16 + 2 * w];
    uint2 h3 = *(const uint2*)&Hs[(size_t)p3 * 16 + 2 * w];
    uint2 h4 = *(const uint2*)&Hs[(size_t)p4 * 16 + 2 * w];
    uint2 h5 = *(const uint2*)&Hs[(size_t)p5 * 16 + 2 * w];
    uint2 h6 = *(const uint2*)&Hs[(size_t)p6 * 16 + 2 * w];
    uint2 h7 = *(const uint2*)&Hs[(size_t)p7 * 16 + 2 * w];
    a0 += bf_lo(h0.x); a1 += bf_hi(h0.x); a2 += bf_lo(h0.y); a3 += bf_hi(h0.y);
    a0 += bf_lo(h1.x); a1 += bf_hi(h1.x); a2 += bf_lo(h1.y); a3 += bf_hi(h1.y);
    a0 += bf_lo(h2.x); a1 += bf_hi(h2.x); a2 += bf_lo(h2.y); a3 += bf_hi(h2.y);
    a0 += bf_lo(h3.x); a1 += bf_hi(h3.x); a2 += bf_lo(h3.y); a3 += bf_hi(h3.y);
    a0 += bf_lo(h4.x); a1 += bf_hi(h4.x); a2 += bf_lo(h4.y); a3 += bf_hi(h4.y);
    a0 += bf_lo(h5.x); a1 += bf_hi(h5.x); a2 += bf_lo(h5.y); a3 += bf_hi(h5.y);
    a0 += bf_lo(h6.x); a1 += bf_hi(h6.x); a2 += bf_lo(h6.y); a3 += bf_hi(h6.y);
    a0 += bf_lo(h7.x); a1 += bf_hi(h7.x); a2 += bf_lo(h7.y); a3 += bf_hi(h7.y);
  }
  for (; e + 4 <= e1; e += 4) {
    uint32_t p0 = epk[e], p1 = epk[e + 1], p2 = epk[e + 2], p3 = epk[e + 3];
    uint2 h0 = *(const uint2*)&Hs[(size_t)p0 * 16 + 2 * w];
    uint2 h1 = *(const uint2*)&Hs[(size_t)p1 * 16 + 2 * w];
    uint2 h2 = *(const uint2*)&Hs[(size_t)p2 * 16 + 2 * w];
    uint2 h3 = *(const uint2*)&Hs[(size_t)p3 * 16 + 2 * w];
    a0 += bf_lo(h0.x); a1 += bf_hi(h0.x); a2 += bf_lo(h0.y); a3 += bf_hi(h0.y);
    a0 += bf_lo(h1.x); a1 += bf_hi(h1.x); a2 += bf_lo(h1.y); a3 += bf_hi(h1.y);
    a0 += bf_lo(h2.x); a1 += bf_hi(h2.x); a2 += bf_lo(h2.y); a3 += bf_hi(h2.y);
    a0 += bf_lo(h3.x); a1 += bf_hi(h3.x); a2 += bf_lo(h3.y); a3 += bf_hi(h3.y);
  }
  for (; e < e1; ++e) {
    uint2 h = *(const uint2*)&Hs[(size_t)epk[e] * 16 + 2 * w];
    a0 += bf_lo(h.x); a1 += bf_hi(h.x); a2 += bf_lo(h.y); a3 += bf_hi(h.y);
  }
  float dc = rsqrtf((float)(e1 - e0) + 1.f);
  uint2 hc = *(const uint2*)&Hs[(size_t)c * 16 + 2 * w];
  float r0 = fmaf(dc, a0 + bf_lo(hc.x), bias[s * 32 + 4 * w + 0]);
  float r1 = fmaf(dc, a1 + bf_hi(hc.x), bias[s * 32 + 4 * w + 1]);
  float r2 = fmaf(dc, a2 + bf_lo(hc.y), bias[s * 32 + 4 * w + 2]);
  float r3 = fmaf(dc, a3 + bf_hi(hc.y), bias[s * 32 + 4 * w + 3]);
  __f4 res; res.x = r0; res.y = r1; res.z = r2; res.w = r3;
  __builtin_nontemporal_store(res, (__f4*)(out + (size_t)c * 64 + s * 32 + 4 * w));
}

extern "C" void kernel_launch(void* const* d_in, const int* in_sizes, int n_in,
                              void* d_out, int out_size, void* d_ws, size_t ws_size,
                              hipStream_t stream) {
  const float* x  = (const float*)d_in[0];
  const void*  ei = d_in[1];
  const float* W0 = (const float*)d_in[2];
  const float* b0 = (const float*)d_in[3];
  const float* W1 = (const float*)d_in[4];
  const float* b1 = (const float*)d_in[5];
  const float* W2 = (const float*)d_in[6];
  const float* b2 = (const float*)d_in[7];
  float* out = (float*)d_out;

  const int n = in_sizes[0] / 128;   // 100000
  const int E = in_sizes[1] / 2;     // 1600000
  const int NB = (n + 511) >> 9;     // buckets of 512 dests (NB <= 256)

  char* ws = (char*)d_ws;
  size_t off = 0;
  auto alloc = [&](size_t bytes) { char* p = ws + off; off = ws_align(off + bytes); return p; };
  int*      bucket_cnt  = (int*)alloc(256 * 4);
  int*      bucket_offs = (int*)alloc(257 * 4);
  int*      gcursor     = (int*)alloc(256 * 4);
  int*      deg         = (int*)alloc((size_t)n * 4);
  int*      offs        = (int*)alloc((size_t)(n + 1) * 4);
  float*    dinv        = (float*)alloc((size_t)n * 4);
  int*      flag        = (int*)alloc(4);
  uint16_t* wf0         = (uint16_t*)alloc(64 * 1024);
  uint16_t* wf1         = (uint16_t*)alloc(64 * 1024);
  uint16_t* wf2         = (uint16_t*)alloc(32 * 1024);
  uint32_t* epk_binned  = (uint32_t*)alloc((size_t)E * 4);
  uint32_t* epk         = (uint32_t*)alloc((size_t)E * 4);
  uint16_t* hbuf        = (uint16_t*)alloc((size_t)n * 128 * 2);  // sliced bf16 H'
  uint32_t* abuf        = (uint32_t*)alloc((size_t)n * 128 * 2);  // sliced bf16 acts
  (void)ws_size;

  hipMemsetAsync(bucket_cnt, 0, 256 * 4, stream);

  // W split/fragment prep (independent of graph passes)
  wprep_k<128><<<32, 64, 0, stream>>>(W0, wf0);
  wprep_k<128><<<32, 64, 0, stream>>>(W1, wf1);
  wprep_k<64><<<16, 64, 0, stream>>>(W2, wf2);

  detect_k<<<1, 64, 0, stream>>>((const int*)ei, flag);
  passA_k<<<1024, 256, 0, stream>>>(ei, flag, bucket_cnt, E, NB);
  bscan_k<<<1, 256, 0, stream>>>(bucket_cnt, bucket_offs, gcursor, NB);
  passB_k<<<(E + 4095) / 4096, 512, 0, stream>>>(ei, flag, gcursor, epk_binned, E, NB);
  passC0_k<<<NB, 1024, 0, stream>>>(epk_binned, bucket_offs, deg, offs, n, NB);
  dinv_k<<<(n + 255) / 256, 256, 0, stream>>>(deg, dinv, n);
  passC_k<<<NB, 1024, 0, stream>>>(epk_binned, bucket_offs, offs, epk);

  const int gemm_blocks = (n + 127) / 128;
  const int agg128_blocks = 4 * ((n + 31) / 32);
  const int ng = (n + 31) >> 5, nq = (ng + 3) >> 2;
  const int agg64_blocks = 8 * nq;

  // Layer 0 (dense fp32 input)
  gemm_k<128, false><<<gemm_blocks, 256, 0, stream>>>(x, wf0, dinv, hbuf, n);
  agg128s_k<<<agg128_blocks, 256, 0, stream>>>((const uint32_t*)hbuf, offs, epk, b0, abuf, 1, n);
  // Layer 1 (bf16 sliced activations, 2-term MFMA)
  gemm_k<128, true><<<gemm_blocks, 256, 0, stream>>>(abuf, wf1, dinv, hbuf, n);
  agg128s_k<<<agg128_blocks, 256, 0, stream>>>((const uint32_t*)hbuf, offs, epk, b1, abuf, 1, n);
  // Layer 2 (no relu) -> d_out dense fp32
  gemm_k<64, true><<<gemm_blocks, 256, 0, stream>>>(abuf, wf2, dinv, hbuf, n);
  agg64s_k<<<agg64_blocks, 256, 0, stream>>>((const uint32_t*)hbuf, offs, epk, b2, out, n);
}